// Round 2
// baseline (2375.756 us; speedup 1.0000x reference)
//
#include <hip/hip_runtime.h>
#include <math.h>

// ---------------- problem constants ----------------
#define Bb     8
#define Cc     256
#define Hh     96
#define Ww     96
#define HEADS  8
#define WS_    12
#define HD     32
#define LL     144           // WS*WS
#define NPIX   9216          // 96*96
#define NPLANE 2048          // B*C
#define NTOK   73728         // 512*144
#define NWIN   512
#define SCALE_ 0.17677669529663687f   // 32^-0.5
#define BN1N   73728.0f
#define GELC   0.7071067811865476f

// workspace layout (floats)
#define OFF_DT    0           // 9216
#define OFF_MT    9216        // 9216
#define OFF_FNM   18432       // 73728
#define OFF_E     92160       // 73728
#define OFF_MASK  165888      // 73728
#define OFF_P3    239616      // 576
#define OFF_ST1   240192      // 2
#define OFF_BN2   240200      // 512
#define OFF_BUF0  262144      // 18874368  (XT -> G)
#define OFF_BUF1  19136512    // 18874368  (QKV -> Y1 -> Z)
#define OFF_BUF2  38010880    // 18874368  (A -> O -> XF)
// total = 56885248 floats = ~228 MB of d_ws

#define QKV_TSEC 4718592      // 512*2*144*32 (per q/k/v section, 2 heads/pass)

static __device__ __forceinline__ float sigm(float x){ return 1.0f/(1.0f+__expf(-x)); }

// ---------------- DCT / IDCT matrices (transposed: [k][i] = P[i][k]) ----------------
__global__ void k_mat(float* Dt, float* Mt){
  int t = blockIdx.x*256 + threadIdx.x;
  if (t < 9216){
    int k = t/96, i = t%96;   // Dt[k][i] = D[i][k] = 2cos(pi*i*(2k+1)/192)
    Dt[t] = (float)(2.0*cos(3.14159265358979323846*(double)i*(double)(2*k+1)/192.0));
  } else if (t < 18432){
    int u = t - 9216;
    int k = u/96, j = u%96;   // Mt[k][j] = M[j][k]
    double v = (k==0) ? 1.0 : 2.0*cos(3.14159265358979323846*(double)k*(double)(2*j+1)/192.0);
    if (k == 94) v += cos(3.14159265358979323846*94.0/192.0) * ((j&1)? -1.0 : 1.0);
    Mt[u] = (float)(v/192.0);
  }
}

// ---------------- batched plane transform  Y = P X Q^T  (per 96x96 plane) ----------------
// mode 0: FNORM  out = (|y|-min)/(max+1e-6)   (per-plane min/max of |y|)
// mode 1: GATE   out = y * sigmoid(5(|y|-mean(y)))
// mode 2: PLAIN  out = y
__global__ __launch_bounds__(256) void k_plane(const float* __restrict__ in, float* __restrict__ out,
                                               const float* __restrict__ Pt, const float* __restrict__ Qt,
                                               int mode){
  __shared__ __align__(16) float Ts[96*98];
  __shared__ __align__(16) float SA[1536];
  __shared__ __align__(16) float SB[1536];
  const int plane = blockIdx.x;
  const int tid = threadIdx.x;
  const int ti = tid>>4, tx = tid&15;
  const int i0 = ti*6, j0 = tx*6;
  const float* src = in + (size_t)plane*NPIX;

  float acc[6][6];
  #pragma unroll
  for (int a=0;a<6;++a){
    #pragma unroll
    for (int b=0;b<6;++b) acc[a][b]=0.f;
  }

  // phase 1: T = P @ X   (contract over spatial rows)
  for (int kc=0; kc<6; ++kc){
    for (int t=tid; t<1536; t+=256){ SA[t] = src[kc*1536+t]; SB[t] = Pt[kc*1536+t]; }
    __syncthreads();
    #pragma unroll
    for (int k=0;k<16;++k){
      float2 a0 = *(const float2*)&SB[k*96+i0];
      float2 a1 = *(const float2*)&SB[k*96+i0+2];
      float2 a2 = *(const float2*)&SB[k*96+i0+4];
      float2 b0 = *(const float2*)&SA[k*96+j0];
      float2 b1 = *(const float2*)&SA[k*96+j0+2];
      float2 b2 = *(const float2*)&SA[k*96+j0+4];
      float av[6] = {a0.x,a0.y,a1.x,a1.y,a2.x,a2.y};
      float bv[6] = {b0.x,b0.y,b1.x,b1.y,b2.x,b2.y};
      #pragma unroll
      for (int ii=0;ii<6;++ii){
        #pragma unroll
        for (int jj=0;jj<6;++jj) acc[ii][jj] = fmaf(av[ii], bv[jj], acc[ii][jj]);
      }
    }
    __syncthreads();
  }
  // store T transposed: Ts[j][i]
  #pragma unroll
  for (int jj=0;jj<6;++jj){
    #pragma unroll
    for (int ii=0;ii<6;++ii) Ts[(j0+jj)*98 + i0+ii] = acc[ii][jj];
  }
  __syncthreads();

  float y[6][6];
  #pragma unroll
  for (int a=0;a<6;++a){
    #pragma unroll
    for (int b=0;b<6;++b) y[a][b]=0.f;
  }

  // phase 2: Y = T @ Q^T  (contract over T's column index, stored as Ts rows)
  for (int kc=0; kc<6; ++kc){
    for (int t=tid; t<1536; t+=256) SA[t] = Qt[kc*1536+t];
    __syncthreads();
    #pragma unroll
    for (int k=0;k<16;++k){
      int kg = kc*16+k;
      float2 a0 = *(const float2*)&Ts[kg*98+i0];
      float2 a1 = *(const float2*)&Ts[kg*98+i0+2];
      float2 a2 = *(const float2*)&Ts[kg*98+i0+4];
      float2 b0 = *(const float2*)&SA[k*96+j0];
      float2 b1 = *(const float2*)&SA[k*96+j0+2];
      float2 b2 = *(const float2*)&SA[k*96+j0+4];
      float av[6] = {a0.x,a0.y,a1.x,a1.y,a2.x,a2.y};
      float bv[6] = {b0.x,b0.y,b1.x,b1.y,b2.x,b2.y};
      #pragma unroll
      for (int ii=0;ii<6;++ii){
        #pragma unroll
        for (int jj=0;jj<6;++jj) y[ii][jj] = fmaf(av[ii], bv[jj], y[ii][jj]);
      }
    }
    __syncthreads();
  }

  float* dst = out + (size_t)plane*NPIX;
  if (mode == 0){
    float lmn = 3.4e38f, lmx = 0.f;
    #pragma unroll
    for (int ii=0;ii<6;++ii){
      #pragma unroll
      for (int jj=0;jj<6;++jj){ float a=fabsf(y[ii][jj]); lmn=fminf(lmn,a); lmx=fmaxf(lmx,a); }
    }
    SB[tid]=lmn; SB[256+tid]=lmx; __syncthreads();
    for (int o=128;o;o>>=1){
      if (tid<o){ SB[tid]=fminf(SB[tid],SB[tid+o]); SB[256+tid]=fmaxf(SB[256+tid],SB[256+tid+o]); }
      __syncthreads();
    }
    float mn = SB[0], inv = 1.f/(SB[256]+1e-6f);
    #pragma unroll
    for (int ii=0;ii<6;++ii){
      #pragma unroll
      for (int jj=0;jj<6;++jj) dst[(i0+ii)*96 + j0+jj] = (fabsf(y[ii][jj])-mn)*inv;
    }
  } else if (mode == 1){
    float ls = 0.f;
    #pragma unroll
    for (int ii=0;ii<6;++ii){
      #pragma unroll
      for (int jj=0;jj<6;++jj) ls += y[ii][jj];
    }
    SB[tid]=ls; __syncthreads();
    for (int o=128;o;o>>=1){ if (tid<o) SB[tid]+=SB[tid+o]; __syncthreads(); }
    float mean = SB[0]*(1.f/9216.f);
    #pragma unroll
    for (int ii=0;ii<6;++ii){
      #pragma unroll
      for (int jj=0;jj<6;++jj){
        float v = y[ii][jj];
        dst[(i0+ii)*96 + j0+jj] = v * sigm(5.f*(fabsf(v)-mean));
      }
    }
  } else {
    #pragma unroll
    for (int ii=0;ii<6;++ii){
      #pragma unroll
      for (int jj=0;jj<6;++jj) dst[(i0+ii)*96 + j0+jj] = y[ii][jj];
    }
  }
}

// ---------------- channel mean of freq_norm ----------------
__global__ void k_chmean(const float* __restrict__ A, float* __restrict__ FNM){
  int px = blockIdx.x*256 + threadIdx.x;      // 0..73727
  int b = px/NPIX, p = px - b*NPIX;
  const float* base = A + (size_t)b*Cc*NPIX + p;
  float s = 0.f;
  #pragma unroll 8
  for (int c=0;c<Cc;++c) s += base[(size_t)c*NPIX];
  FNM[px] = s*(1.f/256.f);
}

// ---------------- 3x3 conv (1ch) + partial BN1 stats ----------------
__global__ void k_conv3(const float* __restrict__ FNM, const float* __restrict__ w9,
                        float* __restrict__ E, float* __restrict__ P3){
  __shared__ float rs[256], rq[256];
  int px = blockIdx.x*256 + threadIdx.x;
  int b = px/NPIX, p = px - b*NPIX;
  int h = p/96, w = p - h*96;
  const float* base = FNM + b*NPIX;
  float a = 0.f;
  #pragma unroll
  for (int dy=0;dy<3;++dy){
    int hh = h+dy-1;
    if (hh>=0 && hh<96){
      #pragma unroll
      for (int dx=0;dx<3;++dx){
        int ww2 = w+dx-1;
        if (ww2>=0 && ww2<96) a = fmaf(base[hh*96+ww2], w9[dy*3+dx], a);
      }
    }
  }
  E[px] = a;
  rs[threadIdx.x]=a; rq[threadIdx.x]=a*a; __syncthreads();
  for (int o=128;o;o>>=1){
    if (threadIdx.x<o){ rs[threadIdx.x]+=rs[threadIdx.x+o]; rq[threadIdx.x]+=rq[threadIdx.x+o]; }
    __syncthreads();
  }
  if (threadIdx.x==0){ P3[2*blockIdx.x]=rs[0]; P3[2*blockIdx.x+1]=rq[0]; }
}

__global__ void k_red576(const float* __restrict__ P3, float* __restrict__ ST1){
  __shared__ float rs[256], rq[256];
  float s=0.f,q=0.f;
  for (int i=threadIdx.x;i<288;i+=256){ s+=P3[2*i]; q+=P3[2*i+1]; }
  rs[threadIdx.x]=s; rq[threadIdx.x]=q; __syncthreads();
  for (int o=128;o;o>>=1){
    if (threadIdx.x<o){ rs[threadIdx.x]+=rs[threadIdx.x+o]; rq[threadIdx.x]+=rq[threadIdx.x+o]; }
    __syncthreads();
  }
  if (threadIdx.x==0){ ST1[0]=rs[0]; ST1[1]=rq[0]; }
}

// ---------------- BN1+relu, pooled, noise_global, mask ----------------
__global__ void k_mask(const float* __restrict__ E, const float* __restrict__ ST1,
                       const float* __restrict__ g1, const float* __restrict__ b1,
                       const float* __restrict__ nw, const float* __restrict__ nb,
                       float* __restrict__ MASK){
  __shared__ float les[NPIX];
  __shared__ float red[256];
  int b = blockIdx.x, tid = threadIdx.x;
  float m = ST1[0]*(1.f/BN1N);
  float v = ST1[1]*(1.f/BN1N) - m*m;
  float rstd = rsqrtf(v + 1e-5f);
  float ga = g1[0], be = b1[0];
  float local = 0.f;
  for (int p=tid;p<NPIX;p+=256){
    float le = fmaxf(0.f, (E[b*NPIX+p]-m)*rstd*ga + be);
    les[p] = le; local += le;
  }
  red[tid]=local; __syncthreads();
  for (int o=128;o;o>>=1){ if (tid<o) red[tid]+=red[tid+o]; __syncthreads(); }
  float ng = sigm(red[0]*(1.f/9216.f)*nw[0] + nb[0]);
  for (int p=tid;p<NPIX;p+=256)
    MASK[b*NPIX+p] = sigm(1.f - les[p]) * ng;
}

// ---------------- NCHW -> NHWC transpose ----------------
__global__ void k_tr(const float* __restrict__ x, float* __restrict__ XT){
  __shared__ float tile[32][33];
  int pt = blockIdx.x*32, ct = blockIdx.y*32, b = blockIdx.z;
  int txd = threadIdx.x, tyd = threadIdx.y;
  #pragma unroll
  for (int q=0;q<4;++q){
    int c = ct + tyd + q*8;
    tile[tyd+q*8][txd] = x[(size_t)(b*Cc+c)*NPIX + pt + txd];
  }
  __syncthreads();
  #pragma unroll
  for (int q=0;q<4;++q){
    int p = pt + tyd + q*8;
    XT[(size_t)(b*NPIX+p)*Cc + ct + txd] = tile[txd][tyd+q*8];
  }
}

// ---------------- qkv GEMM (pass g covers heads 2g, 2g+1; N=192) ----------------
__global__ __launch_bounds__(256) void k_qkv(const float* __restrict__ XT, const float* __restrict__ Wq,
                                             const float* __restrict__ bq, float* __restrict__ qkv, int g){
  __shared__ __align__(16) float As[16*128];
  __shared__ __align__(16) float Bs[16*96];
  const int mt = blockIdx.x, nt = blockIdx.y;
  const int r0 = mt*128;
  const int tid = threadIdx.x;
  const int ty = tid>>4, tx = tid&15;
  float acc[8][6];
  #pragma unroll
  for (int a=0;a<8;++a){
    #pragma unroll
    for (int b=0;b<6;++b) acc[a][b]=0.f;
  }

  for (int k0=0;k0<256;k0+=16){
    #pragma unroll
    for (int it=0;it<2;++it){
      int f = tid + it*256;
      int i = f>>2, kq = f&3;
      int r = r0 + i;
      int win = r/144, l = r - win*144;
      int b = win>>6, wh = (win>>3)&7, wwi = win&7;
      int lh = l/12, lw = l - lh*12;
      int pix = (wh*12+lh)*96 + wwi*12+lw;
      float4 v = *(const float4*)&XT[((size_t)((b*NPIX)+pix))*256 + k0 + (kq<<2)];
      int kk = kq<<2;
      As[(kk+0)*128+i]=v.x; As[(kk+1)*128+i]=v.y; As[(kk+2)*128+i]=v.z; As[(kk+3)*128+i]=v.w;
    }
    #pragma unroll
    for (int it=0;it<2;++it){
      int f = tid + it*256;
      if (f < 384){
        int c = f>>2, kq = f&3;
        int cg = nt*96 + c;
        int t = cg>>6, hl = (cg>>5)&1, d = cg&31;
        int wrow = t*256 + (g*2+hl)*32 + d;
        float4 v = *(const float4*)&Wq[(size_t)wrow*256 + k0 + (kq<<2)];
        int kk = kq<<2;
        Bs[(kk+0)*96+c]=v.x; Bs[(kk+1)*96+c]=v.y; Bs[(kk+2)*96+c]=v.z; Bs[(kk+3)*96+c]=v.w;
      }
    }
    __syncthreads();
    #pragma unroll
    for (int k=0;k<16;++k){
      const float4* pa = (const float4*)&As[k*128 + ty*8];
      float4 a0 = pa[0], a1 = pa[1];
      float av[8] = {a0.x,a0.y,a0.z,a0.w,a1.x,a1.y,a1.z,a1.w};
      const float2* pb = (const float2*)&Bs[k*96];
      float2 b0 = pb[tx], b1 = pb[tx+16], b2 = pb[tx+32];
      float bv[6] = {b0.x,b0.y,b1.x,b1.y,b2.x,b2.y};
      #pragma unroll
      for (int ii=0;ii<8;++ii){
        #pragma unroll
        for (int jj=0;jj<6;++jj) acc[ii][jj] = fmaf(av[ii], bv[jj], acc[ii][jj]);
      }
    }
    __syncthreads();
  }
  #pragma unroll
  for (int ii=0;ii<8;++ii){
    int r = r0 + ty*8 + ii;
    int win = r/144, l = r - win*144;
    #pragma unroll
    for (int jj=0;jj<6;++jj){
      int s = jj>>1;
      int c = nt*96 + 2*tx + s*32 + (jj&1);
      int t = c>>6, hl = (c>>5)&1, d = c&31;
      float val = acc[ii][jj] + bq[t*256 + (g*2+hl)*32 + d];
      qkv[(size_t)t*QKV_TSEC + ((size_t)(win*2+hl)*144 + l)*32 + d] = val;
    }
  }
}

// ---------------- window attention (one block per window x head-local) ----------------
__global__ __launch_bounds__(192) void k_attn(const float* __restrict__ qkv, const float* __restrict__ rpb,
                                              float* __restrict__ O, int g){
  __shared__ __align__(16) float qt[32*144];
  __shared__ __align__(16) float Ks[144*32];
  __shared__ __align__(16) float Vs[144*32];
  __shared__ float rpbs[532];
  const int win = blockIdx.x, hl = blockIdx.y;
  const int head = g*2 + hl;
  const int tid = threadIdx.x;
  const float* Qg = qkv + ((size_t)(win*2+hl)*144)*32;
  const float* Kg = Qg + QKV_TSEC;
  const float* Vg = Qg + 2*(size_t)QKV_TSEC;
  for (int t=tid; t<4608; t+=192){
    Ks[t] = Kg[t]; Vs[t] = Vg[t];
    int l = t>>5, d = t&31;
    qt[d*144+l] = Qg[t];
  }
  for (int t=tid; t<529; t+=192) rpbs[t] = rpb[t*8 + head];
  __syncthreads();

  int r = tid;
  if (r < 144){
    float q[32];
    #pragma unroll
    for (int d=0;d<32;++d) q[d] = qt[d*144+r];
    float o[32];
    #pragma unroll
    for (int d=0;d<32;++d) o[d]=0.f;
    float m = -3.4e38f, sum = 0.f;
    int rh = r/12, rw = r - rh*12;
    int jh = 0, jw = 0;
    for (int j=0;j<144;++j){
      const float4* kp = (const float4*)&Ks[j*32];
      float s0=0,s1=0,s2=0,s3=0;
      #pragma unroll
      for (int t=0;t<8;++t){
        float4 kv = kp[t];
        s0 = fmaf(q[4*t+0],kv.x,s0); s1 = fmaf(q[4*t+1],kv.y,s1);
        s2 = fmaf(q[4*t+2],kv.z,s2); s3 = fmaf(q[4*t+3],kv.w,s3);
      }
      float s = ((s0+s1)+(s2+s3))*SCALE_ + rpbs[(rh-jh+11)*23 + (rw-jw+11)];
      float mn2 = fmaxf(m, s);
      if (mn2 > m){
        float corr = __expf(m - mn2);
        sum *= corr;
        #pragma unroll
        for (int d=0;d<32;++d) o[d]*=corr;
        m = mn2;
      }
      float p = __expf(s - m);
      sum += p;
      const float4* vp = (const float4*)&Vs[j*32];
      #pragma unroll
      for (int t=0;t<8;++t){
        float4 vv = vp[t];
        o[4*t+0]=fmaf(p,vv.x,o[4*t+0]); o[4*t+1]=fmaf(p,vv.y,o[4*t+1]);
        o[4*t+2]=fmaf(p,vv.z,o[4*t+2]); o[4*t+3]=fmaf(p,vv.w,o[4*t+3]);
      }
      if (++jw==12){ jw=0; ++jh; }
    }
    float inv = 1.f/sum;
    float* dst = O + ((size_t)(win*144+r))*256 + head*32;
    #pragma unroll
    for (int t=0;t<8;++t){
      float4 t4 = { o[4*t]*inv, o[4*t+1]*inv, o[4*t+2]*inv, o[4*t+3]*inv };
      *(float4*)&dst[4*t] = t4;
    }
  }
}

// ---------------- depthwise LPE * mask -> Y1 (base for x_attn add) ----------------
__global__ void k_lpe(const float* __restrict__ x, const float* __restrict__ lw,
                      const float* __restrict__ lb, const float* __restrict__ ls,
                      const float* __restrict__ MASK, float* __restrict__ Y1){
  float scale = ls[0];
  for (size_t idx = (size_t)blockIdx.x*256 + threadIdx.x; idx < (size_t)Bb*Cc*NPIX; idx += (size_t)gridDim.x*256){
    int pc = (int)(idx/NPIX); int p = (int)(idx - (size_t)pc*NPIX);
    int b = pc>>8, c = pc&255;
    int h = p/96, w = p - h*96;
    const float* xp = x + (size_t)pc*NPIX;
    const float* wp = lw + c*9;
    float a = 0.f;
    #pragma unroll
    for (int dy=0;dy<3;++dy){
      int hh = h+dy-1;
      if (hh>=0 && hh<96){
        #pragma unroll
        for (int dx=0;dx<3;++dx){
          int ww2 = w+dx-1;
          if (ww2>=0 && ww2<96) a = fmaf(xp[hh*96+ww2], wp[dy*3+dx], a);
        }
      }
    }
    Y1[idx] = (a + lb[c]) * scale * MASK[b*NPIX+p];
  }
}

// ---------------- proj GEMM; Y1 += x_attn (token->image scatter) ----------------
__global__ __launch_bounds__(256) void k_proj(const float* __restrict__ O, const float* __restrict__ Wp,
                                              const float* __restrict__ bp, float* __restrict__ Y1){
  __shared__ __align__(16) float As[16*128];
  __shared__ __align__(16) float Bs[16*128];
  const int mt = blockIdx.x, nt = blockIdx.y;
  const int r0 = mt*128, c0 = nt*128;
  const int tid = threadIdx.x;
  const int ty = tid>>4, tx = tid&15;
  float acc[8][8];
  #pragma unroll
  for (int a=0;a<8;++a){
    #pragma unroll
    for (int b=0;b<8;++b) acc[a][b]=0.f;
  }

  for (int k0=0;k0<256;k0+=16){
    #pragma unroll
    for (int it=0;it<2;++it){
      int f = tid + it*256;
      int i = f>>2, kq = f&3;
      float4 v = *(const float4*)&O[((size_t)(r0+i))*256 + k0 + (kq<<2)];
      int kk = kq<<2;
      As[(kk+0)*128+i]=v.x; As[(kk+1)*128+i]=v.y; As[(kk+2)*128+i]=v.z; As[(kk+3)*128+i]=v.w;
    }
    #pragma unroll
    for (int it=0;it<2;++it){
      int f = tid + it*256;
      int c = f>>2, kq = f&3;
      float4 v = *(const float4*)&Wp[((size_t)(c0+c))*256 + k0 + (kq<<2)];
      int kk = kq<<2;
      Bs[(kk+0)*128+c]=v.x; Bs[(kk+1)*128+c]=v.y; Bs[(kk+2)*128+c]=v.z; Bs[(kk+3)*128+c]=v.w;
    }
    __syncthreads();
    #pragma unroll
    for (int k=0;k<16;++k){
      const float4* pa = (const float4*)&As[k*128 + ty*8];
      float4 a0 = pa[0], a1 = pa[1];
      float av[8] = {a0.x,a0.y,a0.z,a0.w,a1.x,a1.y,a1.z,a1.w};
      const float4* pb = (const float4*)&Bs[k*128];
      float4 b0 = pb[tx], b1 = pb[tx+16];
      float bv[8] = {b0.x,b0.y,b0.z,b0.w,b1.x,b1.y,b1.z,b1.w};
      #pragma unroll
      for (int ii=0;ii<8;++ii){
        #pragma unroll
        for (int jj=0;jj<8;++jj) acc[ii][jj] = fmaf(av[ii], bv[jj], acc[ii][jj]);
      }
    }
    __syncthreads();
  }
  #pragma unroll
  for (int ii=0;ii<8;++ii){
    int r = r0 + ty*8 + ii;
    int win = r/144, l = r - win*144;
    int b = win>>6, wh = (win>>3)&7, wwi = win&7;
    int lh = l/12, lw = l - lh*12;
    int pix = (wh*12+lh)*96 + wwi*12+lw;
    #pragma unroll
    for (int jj=0;jj<8;++jj){
      int co = c0 + ((jj<4)? 4*tx+jj : 64 + 4*tx + (jj-4));
      float* yp = Y1 + ((size_t)(b*Cc+co))*NPIX + pix;
      *yp += acc[ii][jj] + bp[co];
    }
  }
}

// ---------------- 1x1 refine conv: Z = fr_w @ (x + XF) ----------------
__global__ __launch_bounds__(256) void k_conv1x1(const float* __restrict__ x, const float* __restrict__ XF,
                                                 const float* __restrict__ Wf, float* __restrict__ Z){
  __shared__ __align__(16) float As[16*128];
  __shared__ __align__(16) float Bs[16*128];
  const int mt = blockIdx.x, nt = blockIdx.y;
  const int gp0 = mt*128;
  const int b = gp0/NPIX, p0 = gp0 - b*NPIX;
  const int c0 = nt*128;
  const int tid = threadIdx.x;
  const int ty = tid>>4, tx = tid&15;
  float acc[8][8];
  #pragma unroll
  for (int a=0;a<8;++a){
    #pragma unroll
    for (int bb=0;bb<8;++bb) acc[a][bb]=0.f;
  }

  for (int k0=0;k0<256;k0+=16){
    #pragma unroll
    for (int it=0;it<2;++it){
      int f = tid + it*256;          // 0..511 float4s
      int k = f>>5, i4 = f&31;
      size_t off = ((size_t)(b*Cc + k0 + k))*NPIX + p0 + i4*4;
      float4 va = *(const float4*)&x[off];
      float4 vb = *(const float4*)&XF[off];
      float4 s = { va.x+vb.x, va.y+vb.y, va.z+vb.z, va.w+vb.w };
      *(float4*)&As[k*128 + i4*4] = s;
    }
    #pragma unroll
    for (int it=0;it<2;++it){
      int f = tid + it*256;
      int c = f>>2, kq = f&3;
      float4 v = *(const float4*)&Wf[((size_t)(c0+c))*256 + k0 + (kq<<2)];
      int kk = kq<<2;
      Bs[(kk+0)*128+c]=v.x; Bs[(kk+1)*128+c]=v.y; Bs[(kk+2)*128+c]=v.z; Bs[(kk+3)*128+c]=v.w;
    }
    __syncthreads();
    #pragma unroll
    for (int k=0;k<16;++k){
      const float4* pa = (const float4*)&As[k*128 + ty*8];
      float4 a0 = pa[0], a1 = pa[1];
      float av[8] = {a0.x,a0.y,a0.z,a0.w,a1.x,a1.y,a1.z,a1.w};
      const float4* pb = (const float4*)&Bs[k*128];
      float4 b0 = pb[tx], b1 = pb[tx+16];
      float bv[8] = {b0.x,b0.y,b0.z,b0.w,b1.x,b1.y,b1.z,b1.w};
      #pragma unroll
      for (int ii=0;ii<8;++ii){
        #pragma unroll
        for (int jj=0;jj<8;++jj) acc[ii][jj] = fmaf(av[ii], bv[jj], acc[ii][jj]);
      }
    }
    __syncthreads();
  }
  #pragma unroll
  for (int jj=0;jj<8;++jj){
    int co = c0 + ((jj<4)? 4*tx+jj : 64 + 4*tx + (jj-4));
    float4 lo = {acc[0][jj],acc[1][jj],acc[2][jj],acc[3][jj]};
    float4 hi = {acc[4][jj],acc[5][jj],acc[6][jj],acc[7][jj]};
    float* zp = Z + ((size_t)(b*Cc+co))*NPIX + p0 + ty*8;
    *(float4*)zp = lo;
    *(float4*)(zp+4) = hi;
  }
}

// ---------------- BN2 stats (per channel over B,H,W) ----------------
__global__ void k_bnstat(const float* __restrict__ Z, float* __restrict__ BN2){
  __shared__ float rs[256], rq[256];
  int c = blockIdx.x, tid = threadIdx.x;
  float s=0.f,q=0.f;
  for (int b=0;b<Bb;++b){
    const float* pl = Z + ((size_t)(b*Cc+c))*NPIX;
    for (int i=tid;i<NPIX/4;i+=256){
      float4 v = *(const float4*)&pl[i*4];
      s += v.x+v.y+v.z+v.w;
      q += v.x*v.x + v.y*v.y + v.z*v.z + v.w*v.w;
    }
  }
  rs[tid]=s; rq[tid]=q; __syncthreads();
  for (int o=128;o;o>>=1){
    if (tid<o){ rs[tid]+=rs[tid+o]; rq[tid]+=rq[tid+o]; }
    __syncthreads();
  }
  if (tid==0){ BN2[c]=rs[0]; BN2[256+c]=rq[0]; }
}

// ---------------- final: BN2 + exact GELU ----------------
__global__ void k_final(const float* __restrict__ Z, const float* __restrict__ BN2,
                        const float* __restrict__ g2, const float* __restrict__ b2,
                        float* __restrict__ out){
  size_t f4 = (size_t)blockIdx.x*256 + threadIdx.x;   // 4718592 total
  size_t base = f4*4;
  int c = (int)((base/NPIX) & 255);
  float m = BN2[c]*(1.f/BN1N);
  float v = BN2[256+c]*(1.f/BN1N) - m*m;
  float rstd = rsqrtf(v+1e-5f);
  float ga = g2[c], be = b2[c];
  float4 z = *(const float4*)&Z[base];
  float4 r;
  float y;
  y = (z.x-m)*rstd*ga + be; r.x = 0.5f*y*(1.f+erff(y*GELC));
  y = (z.y-m)*rstd*ga + be; r.y = 0.5f*y*(1.f+erff(y*GELC));
  y = (z.z-m)*rstd*ga + be; r.z = 0.5f*y*(1.f+erff(y*GELC));
  y = (z.w-m)*rstd*ga + be; r.w = 0.5f*y*(1.f+erff(y*GELC));
  *(float4*)&out[base] = r;
}

// ---------------- launch ----------------
extern "C" void kernel_launch(void* const* d_in, const int* in_sizes, int n_in,
                              void* d_out, int out_size, void* d_ws, size_t ws_size,
                              hipStream_t stream){
  const float* x      = (const float*)d_in[0];
  const float* qkv_w  = (const float*)d_in[1];
  const float* qkv_b  = (const float*)d_in[2];
  const float* proj_w = (const float*)d_in[3];
  const float* proj_b = (const float*)d_in[4];
  const float* lpe_w  = (const float*)d_in[5];
  const float* lpe_b  = (const float*)d_in[6];
  const float* lpe_s  = (const float*)d_in[7];
  const float* rpb    = (const float*)d_in[8];
  const float* ec_w   = (const float*)d_in[9];
  const float* bn1_g  = (const float*)d_in[10];
  const float* bn1_b  = (const float*)d_in[11];
  const float* nl_w   = (const float*)d_in[12];
  const float* nl_b   = (const float*)d_in[13];
  const float* fr_w   = (const float*)d_in[14];
  const float* bn2_g  = (const float*)d_in[15];
  const float* bn2_b  = (const float*)d_in[16];
  float* outp = (float*)d_out;

  float* WS   = (float*)d_ws;       // needs ~228 MB
  float* Dt   = WS + OFF_DT;
  float* Mt   = WS + OFF_MT;
  float* FNM  = WS + OFF_FNM;
  float* E    = WS + OFF_E;
  float* MASK = WS + OFF_MASK;
  float* P3   = WS + OFF_P3;
  float* ST1  = WS + OFF_ST1;
  float* BN2  = WS + OFF_BN2;
  float* BUF0 = WS + OFF_BUF0;      // XT -> G
  float* BUF1 = WS + OFF_BUF1;      // QKV -> Y1 -> Z
  float* BUF2 = WS + OFF_BUF2;      // A(fn) -> O -> XF

  k_mat<<<72,256,0,stream>>>(Dt, Mt);
  // freq detector: |dct2(x)| plane-normalized -> BUF2
  k_plane<<<NPLANE,256,0,stream>>>(x, BUF2, Dt, Dt, 0);
  k_chmean<<<288,256,0,stream>>>(BUF2, FNM);
  k_conv3<<<288,256,0,stream>>>(FNM, ec_w, E, P3);
  k_red576<<<1,256,0,stream>>>(P3, ST1);
  k_mask<<<8,256,0,stream>>>(E, ST1, bn1_g, bn1_b, nl_w, nl_b, MASK);
  // attention
  k_tr<<<dim3(288,8,8),dim3(32,8),0,stream>>>(x, BUF0);
  for (int g=0; g<4; ++g){
    k_qkv<<<dim3(576,2),256,0,stream>>>(BUF0, qkv_w, qkv_b, BUF1, g);
    k_attn<<<dim3(512,2),192,0,stream>>>(BUF1, rpb, BUF2, g);
  }
  k_lpe<<<4096,256,0,stream>>>(x, lpe_w, lpe_b, lpe_s, MASK, BUF1);   // Y1 = lpe part
  k_proj<<<dim3(576,2),256,0,stream>>>(BUF2, proj_w, proj_b, BUF1);   // Y1 += attn
  // frequency soft gate
  k_plane<<<NPLANE,256,0,stream>>>(BUF1, BUF0, Dt, Dt, 1);            // G = freq2*gate
  k_plane<<<NPLANE,256,0,stream>>>(BUF0, BUF2, Mt, Mt, 2);            // XF = idct2(G)
  // refine + BN2 + gelu
  k_conv1x1<<<dim3(576,2),256,0,stream>>>(x, BUF2, fr_w, BUF1);       // Z
  k_bnstat<<<256,256,0,stream>>>(BUF1, BN2);
  k_final<<<18432,256,0,stream>>>(BUF1, BN2, bn2_g, bn2_b, outp);
}

// Round 3
// 2136.894 us; speedup vs baseline: 1.1118x; 1.1118x over previous
//
#include <hip/hip_runtime.h>
#include <math.h>

// ---------------- problem constants ----------------
#define Bb     8
#define Cc     256
#define Hh     96
#define Ww     96
#define HEADS  8
#define WS_    12
#define HD     32
#define LL     144           // WS*WS
#define NPIX   9216          // 96*96
#define NPLANE 2048          // B*C
#define NTOK   73728         // 512*144
#define NWIN   512
#define SCALE_ 0.17677669529663687f   // 32^-0.5
#define BN1N   73728.0f
#define GELC   0.7071067811865476f

// workspace layout (floats)
#define OFF_DT    0           // 9216
#define OFF_MT    9216        // 9216
#define OFF_FNM   18432       // 73728
#define OFF_E     92160       // 73728
#define OFF_MASK  165888      // 73728
#define OFF_P3    239616      // 576
#define OFF_ST1   240192      // 2
#define OFF_BN2   240200      // 512
#define OFF_BUF0  262144      // 18874368  (XT -> PROJ -> XF)
#define OFF_BUF1  19136512    // 18874368  (QKV -> Y1 -> Z)
#define OFF_BUF2  38010880    // 18874368  (A -> O -> G)
// total = 56885248 floats = ~228 MB of d_ws

#define QKV_TSEC 4718592      // 512*2*144*32 (per q/k/v section, 2 heads/pass)

static __device__ __forceinline__ float sigm(float x){ return 1.0f/(1.0f+__expf(-x)); }

// ---------------- DCT / IDCT matrices (transposed: [k][i] = P[i][k]) ----------------
__global__ void k_mat(float* Dt, float* Mt){
  int t = blockIdx.x*256 + threadIdx.x;
  if (t < 9216){
    int k = t/96, i = t%96;   // Dt[k][i] = D[i][k] = 2cos(pi*i*(2k+1)/192)
    Dt[t] = (float)(2.0*cos(3.14159265358979323846*(double)i*(double)(2*k+1)/192.0));
  } else if (t < 18432){
    int u = t - 9216;
    int k = u/96, j = u%96;   // Mt[k][j] = M[j][k]
    double v = (k==0) ? 1.0 : 2.0*cos(3.14159265358979323846*(double)k*(double)(2*j+1)/192.0);
    if (k == 94) v += cos(3.14159265358979323846*94.0/192.0) * ((j&1)? -1.0 : 1.0);
    Mt[u] = (float)(v/192.0);
  }
}

// ---------------- batched plane transform  Y = P X Q^T  (per 96x96 plane) ----------------
// mode 0: FNORM  out = (|y|-min)/(max+1e-6)   (per-plane min/max of |y|)
// mode 1: GATE   out = y * sigmoid(5(|y|-mean(y)))
// mode 2: PLAIN  out = y
__global__ __launch_bounds__(256) void k_plane(const float* __restrict__ in, float* __restrict__ out,
                                               const float* __restrict__ Pt, const float* __restrict__ Qt,
                                               int mode){
  __shared__ __align__(16) float Ts[96*98];
  __shared__ __align__(16) float SA[1536];
  __shared__ __align__(16) float SB[1536];
  const int plane = blockIdx.x;
  const int tid = threadIdx.x;
  const int ti = tid>>4, tx = tid&15;
  const int i0 = ti*6, j0 = tx*6;
  const float* src = in + (size_t)plane*NPIX;

  float acc[6][6];
  #pragma unroll
  for (int a=0;a<6;++a){
    #pragma unroll
    for (int b=0;b<6;++b) acc[a][b]=0.f;
  }

  // phase 1: T = P @ X   (contract over spatial rows)
  for (int kc=0; kc<6; ++kc){
    for (int t=tid; t<1536; t+=256){ SA[t] = src[kc*1536+t]; SB[t] = Pt[kc*1536+t]; }
    __syncthreads();
    #pragma unroll
    for (int k=0;k<16;++k){
      float2 a0 = *(const float2*)&SB[k*96+i0];
      float2 a1 = *(const float2*)&SB[k*96+i0+2];
      float2 a2 = *(const float2*)&SB[k*96+i0+4];
      float2 b0 = *(const float2*)&SA[k*96+j0];
      float2 b1 = *(const float2*)&SA[k*96+j0+2];
      float2 b2 = *(const float2*)&SA[k*96+j0+4];
      float av[6] = {a0.x,a0.y,a1.x,a1.y,a2.x,a2.y};
      float bv[6] = {b0.x,b0.y,b1.x,b1.y,b2.x,b2.y};
      #pragma unroll
      for (int ii=0;ii<6;++ii){
        #pragma unroll
        for (int jj=0;jj<6;++jj) acc[ii][jj] = fmaf(av[ii], bv[jj], acc[ii][jj]);
      }
    }
    __syncthreads();
  }
  // store T transposed: Ts[j][i]
  #pragma unroll
  for (int jj=0;jj<6;++jj){
    #pragma unroll
    for (int ii=0;ii<6;++ii) Ts[(j0+jj)*98 + i0+ii] = acc[ii][jj];
  }
  __syncthreads();

  float y[6][6];
  #pragma unroll
  for (int a=0;a<6;++a){
    #pragma unroll
    for (int b=0;b<6;++b) y[a][b]=0.f;
  }

  // phase 2: Y = T @ Q^T  (contract over T's column index, stored as Ts rows)
  for (int kc=0; kc<6; ++kc){
    for (int t=tid; t<1536; t+=256) SA[t] = Qt[kc*1536+t];
    __syncthreads();
    #pragma unroll
    for (int k=0;k<16;++k){
      int kg = kc*16+k;
      float2 a0 = *(const float2*)&Ts[kg*98+i0];
      float2 a1 = *(const float2*)&Ts[kg*98+i0+2];
      float2 a2 = *(const float2*)&Ts[kg*98+i0+4];
      float2 b0 = *(const float2*)&SA[k*96+j0];
      float2 b1 = *(const float2*)&SA[k*96+j0+2];
      float2 b2 = *(const float2*)&SA[k*96+j0+4];
      float av[6] = {a0.x,a0.y,a1.x,a1.y,a2.x,a2.y};
      float bv[6] = {b0.x,b0.y,b1.x,b1.y,b2.x,b2.y};
      #pragma unroll
      for (int ii=0;ii<6;++ii){
        #pragma unroll
        for (int jj=0;jj<6;++jj) y[ii][jj] = fmaf(av[ii], bv[jj], y[ii][jj]);
      }
    }
    __syncthreads();
  }

  float* dst = out + (size_t)plane*NPIX;
  if (mode == 0){
    float lmn = 3.4e38f, lmx = 0.f;
    #pragma unroll
    for (int ii=0;ii<6;++ii){
      #pragma unroll
      for (int jj=0;jj<6;++jj){ float a=fabsf(y[ii][jj]); lmn=fminf(lmn,a); lmx=fmaxf(lmx,a); }
    }
    SB[tid]=lmn; SB[256+tid]=lmx; __syncthreads();
    for (int o=128;o;o>>=1){
      if (tid<o){ SB[tid]=fminf(SB[tid],SB[tid+o]); SB[256+tid]=fmaxf(SB[256+tid],SB[256+tid+o]); }
      __syncthreads();
    }
    float mn = SB[0], inv = 1.f/(SB[256]+1e-6f);
    #pragma unroll
    for (int ii=0;ii<6;++ii){
      #pragma unroll
      for (int jj=0;jj<6;++jj) dst[(i0+ii)*96 + j0+jj] = (fabsf(y[ii][jj])-mn)*inv;
    }
  } else if (mode == 1){
    float ls = 0.f;
    #pragma unroll
    for (int ii=0;ii<6;++ii){
      #pragma unroll
      for (int jj=0;jj<6;++jj) ls += y[ii][jj];
    }
    SB[tid]=ls; __syncthreads();
    for (int o=128;o;o>>=1){ if (tid<o) SB[tid]+=SB[tid+o]; __syncthreads(); }
    float mean = SB[0]*(1.f/9216.f);
    #pragma unroll
    for (int ii=0;ii<6;++ii){
      #pragma unroll
      for (int jj=0;jj<6;++jj){
        float v = y[ii][jj];
        dst[(i0+ii)*96 + j0+jj] = v * sigm(5.f*(fabsf(v)-mean));
      }
    }
  } else {
    #pragma unroll
    for (int ii=0;ii<6;++ii){
      #pragma unroll
      for (int jj=0;jj<6;++jj) dst[(i0+ii)*96 + j0+jj] = y[ii][jj];
    }
  }
}

// ---------------- channel mean of freq_norm ----------------
__global__ void k_chmean(const float* __restrict__ A, float* __restrict__ FNM){
  int px = blockIdx.x*256 + threadIdx.x;      // 0..73727
  int b = px/NPIX, p = px - b*NPIX;
  const float* base = A + (size_t)b*Cc*NPIX + p;
  float s = 0.f;
  #pragma unroll 8
  for (int c=0;c<Cc;++c) s += base[(size_t)c*NPIX];
  FNM[px] = s*(1.f/256.f);
}

// ---------------- 3x3 conv (1ch) + partial BN1 stats ----------------
__global__ void k_conv3(const float* __restrict__ FNM, const float* __restrict__ w9,
                        float* __restrict__ E, float* __restrict__ P3){
  __shared__ float rs[256], rq[256];
  int px = blockIdx.x*256 + threadIdx.x;
  int b = px/NPIX, p = px - b*NPIX;
  int h = p/96, w = p - h*96;
  const float* base = FNM + b*NPIX;
  float a = 0.f;
  #pragma unroll
  for (int dy=0;dy<3;++dy){
    int hh = h+dy-1;
    if (hh>=0 && hh<96){
      #pragma unroll
      for (int dx=0;dx<3;++dx){
        int ww2 = w+dx-1;
        if (ww2>=0 && ww2<96) a = fmaf(base[hh*96+ww2], w9[dy*3+dx], a);
      }
    }
  }
  E[px] = a;
  rs[threadIdx.x]=a; rq[threadIdx.x]=a*a; __syncthreads();
  for (int o=128;o;o>>=1){
    if (threadIdx.x<o){ rs[threadIdx.x]+=rs[threadIdx.x+o]; rq[threadIdx.x]+=rq[threadIdx.x+o]; }
    __syncthreads();
  }
  if (threadIdx.x==0){ P3[2*blockIdx.x]=rs[0]; P3[2*blockIdx.x+1]=rq[0]; }
}

__global__ void k_red576(const float* __restrict__ P3, float* __restrict__ ST1){
  __shared__ float rs[256], rq[256];
  float s=0.f,q=0.f;
  for (int i=threadIdx.x;i<288;i+=256){ s+=P3[2*i]; q+=P3[2*i+1]; }
  rs[threadIdx.x]=s; rq[threadIdx.x]=q; __syncthreads();
  for (int o=128;o;o>>=1){
    if (threadIdx.x<o){ rs[threadIdx.x]+=rs[threadIdx.x+o]; rq[threadIdx.x]+=rq[threadIdx.x+o]; }
    __syncthreads();
  }
  if (threadIdx.x==0){ ST1[0]=rs[0]; ST1[1]=rq[0]; }
}

// ---------------- BN1+relu, pooled, noise_global, mask ----------------
__global__ void k_mask(const float* __restrict__ E, const float* __restrict__ ST1,
                       const float* __restrict__ g1, const float* __restrict__ b1,
                       const float* __restrict__ nw, const float* __restrict__ nb,
                       float* __restrict__ MASK){
  __shared__ float les[NPIX];
  __shared__ float red[256];
  int b = blockIdx.x, tid = threadIdx.x;
  float m = ST1[0]*(1.f/BN1N);
  float v = ST1[1]*(1.f/BN1N) - m*m;
  float rstd = rsqrtf(v + 1e-5f);
  float ga = g1[0], be = b1[0];
  float local = 0.f;
  for (int p=tid;p<NPIX;p+=256){
    float le = fmaxf(0.f, (E[b*NPIX+p]-m)*rstd*ga + be);
    les[p] = le; local += le;
  }
  red[tid]=local; __syncthreads();
  for (int o=128;o;o>>=1){ if (tid<o) red[tid]+=red[tid+o]; __syncthreads(); }
  float ng = sigm(red[0]*(1.f/9216.f)*nw[0] + nb[0]);
  for (int p=tid;p<NPIX;p+=256)
    MASK[b*NPIX+p] = sigm(1.f - les[p]) * ng;
}

// ---------------- NCHW -> NHWC transpose ----------------
__global__ void k_tr(const float* __restrict__ x, float* __restrict__ XT){
  __shared__ float tile[32][33];
  int pt = blockIdx.x*32, ct = blockIdx.y*32, b = blockIdx.z;
  int txd = threadIdx.x, tyd = threadIdx.y;
  #pragma unroll
  for (int q=0;q<4;++q){
    int c = ct + tyd + q*8;
    tile[tyd+q*8][txd] = x[(size_t)(b*Cc+c)*NPIX + pt + txd];
  }
  __syncthreads();
  #pragma unroll
  for (int q=0;q<4;++q){
    int p = pt + tyd + q*8;
    XT[(size_t)(b*NPIX+p)*Cc + ct + txd] = tile[txd][tyd+q*8];
  }
}

// ---------------- qkv GEMM (pass g covers heads 2g, 2g+1; N=192) ----------------
__global__ __launch_bounds__(256) void k_qkv(const float* __restrict__ XT, const float* __restrict__ Wq,
                                             const float* __restrict__ bq, float* __restrict__ qkv, int g){
  __shared__ __align__(16) float As[16*128];
  __shared__ __align__(16) float Bs[16*96];
  const int mt = blockIdx.x, nt = blockIdx.y;
  const int r0 = mt*128;
  const int tid = threadIdx.x;
  const int ty = tid>>4, tx = tid&15;
  float acc[8][6];
  #pragma unroll
  for (int a=0;a<8;++a){
    #pragma unroll
    for (int b=0;b<6;++b) acc[a][b]=0.f;
  }

  for (int k0=0;k0<256;k0+=16){
    #pragma unroll
    for (int it=0;it<2;++it){
      int f = tid + it*256;
      int i = f>>2, kq = f&3;
      int r = r0 + i;
      int win = r/144, l = r - win*144;
      int b = win>>6, wh = (win>>3)&7, wwi = win&7;
      int lh = l/12, lw = l - lh*12;
      int pix = (wh*12+lh)*96 + wwi*12+lw;
      float4 v = *(const float4*)&XT[((size_t)((b*NPIX)+pix))*256 + k0 + (kq<<2)];
      int kk = kq<<2;
      As[(kk+0)*128+i]=v.x; As[(kk+1)*128+i]=v.y; As[(kk+2)*128+i]=v.z; As[(kk+3)*128+i]=v.w;
    }
    #pragma unroll
    for (int it=0;it<2;++it){
      int f = tid + it*256;
      if (f < 384){
        int c = f>>2, kq = f&3;
        int cg = nt*96 + c;
        int t = cg>>6, hl = (cg>>5)&1, d = cg&31;
        int wrow = t*256 + (g*2+hl)*32 + d;
        float4 v = *(const float4*)&Wq[(size_t)wrow*256 + k0 + (kq<<2)];
        int kk = kq<<2;
        Bs[(kk+0)*96+c]=v.x; Bs[(kk+1)*96+c]=v.y; Bs[(kk+2)*96+c]=v.z; Bs[(kk+3)*96+c]=v.w;
      }
    }
    __syncthreads();
    #pragma unroll
    for (int k=0;k<16;++k){
      const float4* pa = (const float4*)&As[k*128 + ty*8];
      float4 a0 = pa[0], a1 = pa[1];
      float av[8] = {a0.x,a0.y,a0.z,a0.w,a1.x,a1.y,a1.z,a1.w};
      const float2* pb = (const float2*)&Bs[k*96];
      float2 b0 = pb[tx], b1 = pb[tx+16], b2 = pb[tx+32];
      float bv[6] = {b0.x,b0.y,b1.x,b1.y,b2.x,b2.y};
      #pragma unroll
      for (int ii=0;ii<8;++ii){
        #pragma unroll
        for (int jj=0;jj<6;++jj) acc[ii][jj] = fmaf(av[ii], bv[jj], acc[ii][jj]);
      }
    }
    __syncthreads();
  }
  #pragma unroll
  for (int ii=0;ii<8;++ii){
    int r = r0 + ty*8 + ii;
    int win = r/144, l = r - win*144;
    #pragma unroll
    for (int jj=0;jj<6;++jj){
      int s = jj>>1;
      int c = nt*96 + 2*tx + s*32 + (jj&1);
      int t = c>>6, hl = (c>>5)&1, d = c&31;
      float val = acc[ii][jj] + bq[t*256 + (g*2+hl)*32 + d];
      qkv[(size_t)t*QKV_TSEC + ((size_t)(win*2+hl)*144 + l)*32 + d] = val;
    }
  }
}

// ---------------- window attention (one block per window x head-local) ----------------
__global__ __launch_bounds__(192) void k_attn(const float* __restrict__ qkv, const float* __restrict__ rpb,
                                              float* __restrict__ O, int g){
  __shared__ __align__(16) float qt[32*144];
  __shared__ __align__(16) float Ks[144*32];
  __shared__ __align__(16) float Vs[144*32];
  __shared__ float rpbs[532];
  const int win = blockIdx.x, hl = blockIdx.y;
  const int head = g*2 + hl;
  const int tid = threadIdx.x;
  const float* Qg = qkv + ((size_t)(win*2+hl)*144)*32;
  const float* Kg = Qg + QKV_TSEC;
  const float* Vg = Qg + 2*(size_t)QKV_TSEC;
  for (int t=tid; t<4608; t+=192){
    Ks[t] = Kg[t]; Vs[t] = Vg[t];
    int l = t>>5, d = t&31;
    qt[d*144+l] = Qg[t];
  }
  for (int t=tid; t<529; t+=192) rpbs[t] = rpb[t*8 + head];
  __syncthreads();

  int r = tid;
  if (r < 144){
    float q[32];
    #pragma unroll
    for (int d=0;d<32;++d) q[d] = qt[d*144+r];
    float o[32];
    #pragma unroll
    for (int d=0;d<32;++d) o[d]=0.f;
    float m = -3.4e38f, sum = 0.f;
    int rh = r/12, rw = r - rh*12;
    int jh = 0, jw = 0;
    for (int j=0;j<144;++j){
      const float4* kp = (const float4*)&Ks[j*32];
      float s0=0,s1=0,s2=0,s3=0;
      #pragma unroll
      for (int t=0;t<8;++t){
        float4 kv = kp[t];
        s0 = fmaf(q[4*t+0],kv.x,s0); s1 = fmaf(q[4*t+1],kv.y,s1);
        s2 = fmaf(q[4*t+2],kv.z,s2); s3 = fmaf(q[4*t+3],kv.w,s3);
      }
      float s = ((s0+s1)+(s2+s3))*SCALE_ + rpbs[(rh-jh+11)*23 + (rw-jw+11)];
      float mn2 = fmaxf(m, s);
      if (mn2 > m){
        float corr = __expf(m - mn2);
        sum *= corr;
        #pragma unroll
        for (int d=0;d<32;++d) o[d]*=corr;
        m = mn2;
      }
      float p = __expf(s - m);
      sum += p;
      const float4* vp = (const float4*)&Vs[j*32];
      #pragma unroll
      for (int t=0;t<8;++t){
        float4 vv = vp[t];
        o[4*t+0]=fmaf(p,vv.x,o[4*t+0]); o[4*t+1]=fmaf(p,vv.y,o[4*t+1]);
        o[4*t+2]=fmaf(p,vv.z,o[4*t+2]); o[4*t+3]=fmaf(p,vv.w,o[4*t+3]);
      }
      if (++jw==12){ jw=0; ++jh; }
    }
    float inv = 1.f/sum;
    float* dst = O + ((size_t)(win*144+r))*256 + head*32;
    #pragma unroll
    for (int t=0;t<8;++t){
      float4 t4 = { o[4*t]*inv, o[4*t+1]*inv, o[4*t+2]*inv, o[4*t+3]*inv };
      *(float4*)&dst[4*t] = t4;
    }
  }
}

// ---------------- depthwise LPE * mask -> Y1 += ----------------
__global__ void k_lpe(const float* __restrict__ x, const float* __restrict__ lw,
                      const float* __restrict__ lb, const float* __restrict__ ls,
                      const float* __restrict__ MASK, float* __restrict__ Y1){
  float scale = ls[0];
  for (size_t idx = (size_t)blockIdx.x*256 + threadIdx.x; idx < (size_t)Bb*Cc*NPIX; idx += (size_t)gridDim.x*256){
    int pc = (int)(idx/NPIX); int p = (int)(idx - (size_t)pc*NPIX);
    int b = pc>>8, c = pc&255;
    int h = p/96, w = p - h*96;
    const float* xp = x + (size_t)pc*NPIX;
    const float* wp = lw + c*9;
    float a = 0.f;
    #pragma unroll
    for (int dy=0;dy<3;++dy){
      int hh = h+dy-1;
      if (hh>=0 && hh<96){
        #pragma unroll
        for (int dx=0;dx<3;++dx){
          int ww2 = w+dx-1;
          if (ww2>=0 && ww2<96) a = fmaf(xp[hh*96+ww2], wp[dy*3+dx], a);
        }
      }
    }
    Y1[idx] += (a + lb[c]) * scale * MASK[b*NPIX+p];
  }
}

// ---------------- proj GEMM -> PROJ token-major [token][256], bias fused ----------------
__global__ __launch_bounds__(256) void k_proj(const float* __restrict__ O, const float* __restrict__ Wp,
                                              const float* __restrict__ bp, float* __restrict__ PROJ){
  __shared__ __align__(16) float As[16*128];
  __shared__ __align__(16) float Bs[16*128];
  const int mt = blockIdx.x, nt = blockIdx.y;
  const int r0 = mt*128, c0 = nt*128;
  const int tid = threadIdx.x;
  const int ty = tid>>4, tx = tid&15;
  float acc[8][8];
  #pragma unroll
  for (int a=0;a<8;++a){
    #pragma unroll
    for (int b=0;b<8;++b) acc[a][b]=0.f;
  }

  for (int k0=0;k0<256;k0+=16){
    #pragma unroll
    for (int it=0;it<2;++it){
      int f = tid + it*256;
      int i = f>>2, kq = f&3;
      float4 v = *(const float4*)&O[((size_t)(r0+i))*256 + k0 + (kq<<2)];
      int kk = kq<<2;
      As[(kk+0)*128+i]=v.x; As[(kk+1)*128+i]=v.y; As[(kk+2)*128+i]=v.z; As[(kk+3)*128+i]=v.w;
    }
    #pragma unroll
    for (int it=0;it<2;++it){
      int f = tid + it*256;
      int c = f>>2, kq = f&3;
      float4 v = *(const float4*)&Wp[((size_t)(c0+c))*256 + k0 + (kq<<2)];
      int kk = kq<<2;
      Bs[(kk+0)*128+c]=v.x; Bs[(kk+1)*128+c]=v.y; Bs[(kk+2)*128+c]=v.z; Bs[(kk+3)*128+c]=v.w;
    }
    __syncthreads();
    #pragma unroll
    for (int k=0;k<16;++k){
      const float4* pa = (const float4*)&As[k*128 + ty*8];
      float4 a0 = pa[0], a1 = pa[1];
      float av[8] = {a0.x,a0.y,a0.z,a0.w,a1.x,a1.y,a1.z,a1.w};
      const float4* pb = (const float4*)&Bs[k*128];
      float4 b0 = pb[tx], b1 = pb[tx+16];
      float bv[8] = {b0.x,b0.y,b0.z,b0.w,b1.x,b1.y,b1.z,b1.w};
      #pragma unroll
      for (int ii=0;ii<8;++ii){
        #pragma unroll
        for (int jj=0;jj<8;++jj) acc[ii][jj] = fmaf(av[ii], bv[jj], acc[ii][jj]);
      }
    }
    __syncthreads();
  }
  // coalesced token-major epilogue: channels 4*tx..4*tx+3 and 64+4*tx..64+4*tx+3
  const float4 bp0 = *(const float4*)&bp[c0 + 4*tx];
  const float4 bp1 = *(const float4*)&bp[c0 + 64 + 4*tx];
  #pragma unroll
  for (int ii=0;ii<8;++ii){
    int r = r0 + ty*8 + ii;
    float* pp = PROJ + (size_t)r*256 + c0;
    float4 v0 = { acc[ii][0]+bp0.x, acc[ii][1]+bp0.y, acc[ii][2]+bp0.z, acc[ii][3]+bp0.w };
    float4 v1 = { acc[ii][4]+bp1.x, acc[ii][5]+bp1.y, acc[ii][6]+bp1.z, acc[ii][7]+bp1.w };
    *(float4*)&pp[4*tx] = v0;
    *(float4*)&pp[64 + 4*tx] = v1;
  }
}

// ---------------- token-major PROJ -> NCHW Y1 (LDS transpose) ----------------
__global__ __launch_bounds__(256) void k_merge(const float* __restrict__ PROJ, float* __restrict__ Y1){
  __shared__ float T[96*65];
  const int bx = blockIdx.x;          // b*96 + h
  const int b = bx/96, h = bx - b*96;
  const int wh = h/12, lh = h - wh*12;
  const int c0 = blockIdx.y*64;
  const int t = threadIdx.x;
  const int wave = t>>6, lane = t&63;
  // load 96 token-rows x 64 channels (256B coalesced per wave)
  for (int it=0; it<24; ++it){
    int tok = wave*24 + it;
    int wwi = tok/12, lw = tok - wwi*12;
    int gtok = (b*64 + wh*8 + wwi)*144 + lh*12 + lw;
    T[tok*65 + lane] = PROJ[(size_t)gtok*256 + c0 + lane];
  }
  __syncthreads();
  const int cl = t>>2, p0 = (t&3)*24;
  float* dst = Y1 + ((size_t)(b*Cc + c0 + cl))*NPIX + h*96 + p0;
  #pragma unroll
  for (int i=0;i<24;i+=4){
    float4 v = { T[(p0+i)*65+cl], T[(p0+i+1)*65+cl], T[(p0+i+2)*65+cl], T[(p0+i+3)*65+cl] };
    *(float4*)&dst[i] = v;
  }
}

// ---------------- 1x1 refine conv: Z = fr_w @ (x + XF) ----------------
__global__ __launch_bounds__(256) void k_conv1x1(const float* __restrict__ x, const float* __restrict__ XF,
                                                 const float* __restrict__ Wf, float* __restrict__ Z){
  __shared__ __align__(16) float As[16*128];
  __shared__ __align__(16) float Bs[16*128];
  const int mt = blockIdx.x, nt = blockIdx.y;
  const int gp0 = mt*128;
  const int b = gp0/NPIX, p0 = gp0 - b*NPIX;
  const int c0 = nt*128;
  const int tid = threadIdx.x;
  const int ty = tid>>4, tx = tid&15;
  float acc[8][8];
  #pragma unroll
  for (int a=0;a<8;++a){
    #pragma unroll
    for (int bb=0;bb<8;++bb) acc[a][bb]=0.f;
  }

  for (int k0=0;k0<256;k0+=16){
    #pragma unroll
    for (int it=0;it<2;++it){
      int f = tid + it*256;          // 0..511 float4s
      int k = f>>5, i4 = f&31;
      size_t off = ((size_t)(b*Cc + k0 + k))*NPIX + p0 + i4*4;
      float4 va = *(const float4*)&x[off];
      float4 vb = *(const float4*)&XF[off];
      float4 s = { va.x+vb.x, va.y+vb.y, va.z+vb.z, va.w+vb.w };
      *(float4*)&As[k*128 + i4*4] = s;
    }
    #pragma unroll
    for (int it=0;it<2;++it){
      int f = tid + it*256;
      int c = f>>2, kq = f&3;
      float4 v = *(const float4*)&Wf[((size_t)(c0+c))*256 + k0 + (kq<<2)];
      int kk = kq<<2;
      Bs[(kk+0)*128+c]=v.x; Bs[(kk+1)*128+c]=v.y; Bs[(kk+2)*128+c]=v.z; Bs[(kk+3)*128+c]=v.w;
    }
    __syncthreads();
    #pragma unroll
    for (int k=0;k<16;++k){
      const float4* pa = (const float4*)&As[k*128 + ty*8];
      float4 a0 = pa[0], a1 = pa[1];
      float av[8] = {a0.x,a0.y,a0.z,a0.w,a1.x,a1.y,a1.z,a1.w};
      const float4* pb = (const float4*)&Bs[k*128];
      float4 b0 = pb[tx], b1 = pb[tx+16];
      float bv[8] = {b0.x,b0.y,b0.z,b0.w,b1.x,b1.y,b1.z,b1.w};
      #pragma unroll
      for (int ii=0;ii<8;++ii){
        #pragma unroll
        for (int jj=0;jj<8;++jj) acc[ii][jj] = fmaf(av[ii], bv[jj], acc[ii][jj]);
      }
    }
    __syncthreads();
  }
  #pragma unroll
  for (int jj=0;jj<8;++jj){
    int co = c0 + ((jj<4)? 4*tx+jj : 64 + 4*tx + (jj-4));
    float4 lo = {acc[0][jj],acc[1][jj],acc[2][jj],acc[3][jj]};
    float4 hi = {acc[4][jj],acc[5][jj],acc[6][jj],acc[7][jj]};
    float* zp = Z + ((size_t)(b*Cc+co))*NPIX + p0 + ty*8;
    *(float4*)zp = lo;
    *(float4*)(zp+4) = hi;
  }
}

// ---------------- BN2 stats (per channel over B,H,W) ----------------
__global__ void k_bnstat(const float* __restrict__ Z, float* __restrict__ BN2){
  __shared__ float rs[256], rq[256];
  int c = blockIdx.x, tid = threadIdx.x;
  float s=0.f,q=0.f;
  for (int b=0;b<Bb;++b){
    const float* pl = Z + ((size_t)(b*Cc+c))*NPIX;
    for (int i=tid;i<NPIX/4;i+=256){
      float4 v = *(const float4*)&pl[i*4];
      s += v.x+v.y+v.z+v.w;
      q += v.x*v.x + v.y*v.y + v.z*v.z + v.w*v.w;
    }
  }
  rs[tid]=s; rq[tid]=q; __syncthreads();
  for (int o=128;o;o>>=1){
    if (tid<o){ rs[tid]+=rs[tid+o]; rq[tid]+=rq[tid+o]; }
    __syncthreads();
  }
  if (tid==0){ BN2[c]=rs[0]; BN2[256+c]=rq[0]; }
}

// ---------------- final: BN2 + exact GELU ----------------
__global__ void k_final(const float* __restrict__ Z, const float* __restrict__ BN2,
                        const float* __restrict__ g2, const float* __restrict__ b2,
                        float* __restrict__ out){
  size_t f4 = (size_t)blockIdx.x*256 + threadIdx.x;   // 4718592 total
  size_t base = f4*4;
  int c = (int)((base/NPIX) & 255);
  float m = BN2[c]*(1.f/BN1N);
  float v = BN2[256+c]*(1.f/BN1N) - m*m;
  float rstd = rsqrtf(v+1e-5f);
  float ga = g2[c], be = b2[c];
  float4 z = *(const float4*)&Z[base];
  float4 r;
  float y;
  y = (z.x-m)*rstd*ga + be; r.x = 0.5f*y*(1.f+erff(y*GELC));
  y = (z.y-m)*rstd*ga + be; r.y = 0.5f*y*(1.f+erff(y*GELC));
  y = (z.z-m)*rstd*ga + be; r.z = 0.5f*y*(1.f+erff(y*GELC));
  y = (z.w-m)*rstd*ga + be; r.w = 0.5f*y*(1.f+erff(y*GELC));
  *(float4*)&out[base] = r;
}

// ---------------- launch ----------------
extern "C" void kernel_launch(void* const* d_in, const int* in_sizes, int n_in,
                              void* d_out, int out_size, void* d_ws, size_t ws_size,
                              hipStream_t stream){
  const float* x      = (const float*)d_in[0];
  const float* qkv_w  = (const float*)d_in[1];
  const float* qkv_b  = (const float*)d_in[2];
  const float* proj_w = (const float*)d_in[3];
  const float* proj_b = (const float*)d_in[4];
  const float* lpe_w  = (const float*)d_in[5];
  const float* lpe_b  = (const float*)d_in[6];
  const float* lpe_s  = (const float*)d_in[7];
  const float* rpb    = (const float*)d_in[8];
  const float* ec_w   = (const float*)d_in[9];
  const float* bn1_g  = (const float*)d_in[10];
  const float* bn1_b  = (const float*)d_in[11];
  const float* nl_w   = (const float*)d_in[12];
  const float* nl_b   = (const float*)d_in[13];
  const float* fr_w   = (const float*)d_in[14];
  const float* bn2_g  = (const float*)d_in[15];
  const float* bn2_b  = (const float*)d_in[16];
  float* outp = (float*)d_out;

  float* WS   = (float*)d_ws;       // needs ~228 MB
  float* Dt   = WS + OFF_DT;
  float* Mt   = WS + OFF_MT;
  float* FNM  = WS + OFF_FNM;
  float* E    = WS + OFF_E;
  float* MASK = WS + OFF_MASK;
  float* P3   = WS + OFF_P3;
  float* ST1  = WS + OFF_ST1;
  float* BN2  = WS + OFF_BN2;
  float* BUF0 = WS + OFF_BUF0;      // XT -> PROJ -> XF
  float* BUF1 = WS + OFF_BUF1;      // QKV -> Y1 -> Z
  float* BUF2 = WS + OFF_BUF2;      // A(fn) -> O -> G

  k_mat<<<72,256,0,stream>>>(Dt, Mt);
  // freq detector: |dct2(x)| plane-normalized -> BUF2
  k_plane<<<NPLANE,256,0,stream>>>(x, BUF2, Dt, Dt, 0);
  k_chmean<<<288,256,0,stream>>>(BUF2, FNM);
  k_conv3<<<288,256,0,stream>>>(FNM, ec_w, E, P3);
  k_red576<<<1,256,0,stream>>>(P3, ST1);
  k_mask<<<8,256,0,stream>>>(E, ST1, bn1_g, bn1_b, nl_w, nl_b, MASK);
  // attention
  k_tr<<<dim3(288,8,8),dim3(32,8),0,stream>>>(x, BUF0);
  for (int g=0; g<4; ++g){
    k_qkv<<<dim3(576,2),256,0,stream>>>(BUF0, qkv_w, qkv_b, BUF1, g);
    k_attn<<<dim3(512,2),192,0,stream>>>(BUF1, rpb, BUF2, g);
  }
  k_proj<<<dim3(576,2),256,0,stream>>>(BUF2, proj_w, proj_b, BUF0);   // PROJ token-major
  k_merge<<<dim3(768,4),256,0,stream>>>(BUF0, BUF1);                  // Y1 = attn (NCHW)
  k_lpe<<<4096,256,0,stream>>>(x, lpe_w, lpe_b, lpe_s, MASK, BUF1);   // Y1 += lpe*mask
  // frequency soft gate
  k_plane<<<NPLANE,256,0,stream>>>(BUF1, BUF2, Dt, Dt, 1);            // G = freq2*gate
  k_plane<<<NPLANE,256,0,stream>>>(BUF2, BUF0, Mt, Mt, 2);            // XF = idct2(G)
  // refine + BN2 + gelu
  k_conv1x1<<<dim3(576,2),256,0,stream>>>(x, BUF0, fr_w, BUF1);       // Z
  k_bnstat<<<256,256,0,stream>>>(BUF1, BN2);
  k_final<<<18432,256,0,stream>>>(BUF1, BN2, bn2_g, bn2_b, outp);
}

// Round 4
// 1827.519 us; speedup vs baseline: 1.3000x; 1.1693x over previous
//
#include <hip/hip_runtime.h>
#include <math.h>

// ---------------- problem constants ----------------
#define Bb     8
#define Cc     256
#define Hh     96
#define Ww     96
#define HEADS  8
#define WS_    12
#define HD     32
#define LL     144           // WS*WS
#define NPIX   9216          // 96*96
#define NPLANE 2048          // B*C
#define NTOK   73728         // 512*144
#define NWIN   512
#define SCALE_ 0.17677669529663687f   // 32^-0.5
#define BN1N   73728.0f
#define GELC   0.7071067811865476f

// workspace layout (floats)
#define OFF_DT    0           // frag tables live here (4 x 9216 shorts = 73728 B)
#define OFF_FNM   18432       // 73728
#define OFF_E     92160       // 73728
#define OFF_MASK  165888      // 73728
#define OFF_P3    239616      // 576
#define OFF_ST1   240192      // 2
#define OFF_BN2   240200      // 512
#define OFF_BUF0  262144      // 18874368  (XT -> PROJ -> XF)
#define OFF_BUF1  19136512    // 18874368  (QKV -> Y1 -> Z)
#define OFF_BUF2  38010880    // 18874368  (A -> O -> G)

#define QKV_TSEC 4718592      // 512*2*144*32 (per q/k/v section, 2 heads/pass)

typedef short bf16x8 __attribute__((ext_vector_type(8)));
typedef short s16x4  __attribute__((ext_vector_type(4)));
typedef float f32x4  __attribute__((ext_vector_type(4)));

static __device__ __forceinline__ float sigm(float x){ return 1.0f/(1.0f+__expf(-x)); }

// split fp32 into bf16 hi + bf16 lo (truncation; residual ~2^-16 relative)
static __device__ __forceinline__ void split2(float f, short& h, short& l){
  unsigned u = __float_as_uint(f);
  unsigned hb = u & 0xffff0000u;
  h = (short)(hb>>16);
  float lo = f - __uint_as_float(hb);
  l = (short)(__float_as_uint(lo)>>16);
}

// ---------------- DCT / IDCT matrices in MFMA B-fragment layout, bf16 hi/lo ----------------
// F[k][n]: k = contraction index (32*kt + 8*lr + jj), n = output index (16*nt + (n&15))
// frag idx = ((kt*6+nt)*64 + (lr*16 + (n&15)))*8 + jj
__global__ void k_mat(short* DFh, short* DFl, short* MFh, short* MFl){
  int t = blockIdx.x*256 + threadIdx.x;     // 0..18431
  int m = t/9216, u = t - m*9216;
  int k = u/96, n = u - k*96;
  double v;
  if (m == 0){
    v = 2.0*cos(3.14159265358979323846*(double)n*(double)(2*k+1)/192.0);
  } else {
    v = (k==0) ? 1.0 : 2.0*cos(3.14159265358979323846*(double)k*(double)(2*n+1)/192.0);
    if (k == 94) v += cos(3.14159265358979323846*94.0/192.0) * ((n&1)? -1.0 : 1.0);
    v /= 192.0;
  }
  float f = (float)v;
  short hs, ls; split2(f, hs, ls);
  int kt = k>>5, lr = (k>>3)&3, jj = k&7, nt = n>>4;
  int idx = ((kt*6+nt)*64 + (lr*16 + (n&15)))*8 + jj;
  if (m == 0){ DFh[idx]=hs; DFl[idx]=ls; }
  else       { MFh[idx]=hs; MFl[idx]=ls; }
}

// ---------------- batched plane transform  Y = F^T X F  via MFMA (split-bf16) ----------------
// phase1: TT = X^T * F  (A = X^T from LDS, B = F frags from global)
// phase2: Y  = T * F
// mode 0: FNORM  out = (|y|-min)/(max+1e-6);  mode 1: GATE y*sigm(5(|y|-mean));  mode 2: PLAIN
__global__ __launch_bounds__(256) void k_plane(const float* __restrict__ in, float* __restrict__ out,
                                               const short* __restrict__ Fh, const short* __restrict__ Fl,
                                               int mode){
  __shared__ __align__(16) short Xh[96*104];
  __shared__ __align__(16) short Xl[96*104];
  __shared__ float red[512];
  const int tid = threadIdx.x;
  const int lane = tid & 63, wid = tid >> 6;
  const int l15 = lane & 15, l4 = lane >> 4;
  const float* src = in + (size_t)blockIdx.x*NPIX;

  // stage X transposed: Xh[col][row] (bf16 hi), Xl (lo); 4x4 register transpose per thread
  for (int t4 = tid; t4 < 576; t4 += 256){
    int rt = t4/24, ct = t4 - rt*24;
    const float* p0 = src + rt*4*96 + ct*4;
    float4 v0 = *(const float4*)(p0);
    float4 v1 = *(const float4*)(p0+96);
    float4 v2 = *(const float4*)(p0+192);
    float4 v3 = *(const float4*)(p0+288);
#define STCOL(f0,f1,f2,f3,j) { s16x4 hv, lv; short hs, ls; \
    split2(f0,hs,ls); hv[0]=hs; lv[0]=ls; \
    split2(f1,hs,ls); hv[1]=hs; lv[1]=ls; \
    split2(f2,hs,ls); hv[2]=hs; lv[2]=ls; \
    split2(f3,hs,ls); hv[3]=hs; lv[3]=ls; \
    int cc = ct*4+(j); \
    *(s16x4*)&Xh[cc*104 + rt*4] = hv; \
    *(s16x4*)&Xl[cc*104 + rt*4] = lv; }
    STCOL(v0.x,v1.x,v2.x,v3.x,0)
    STCOL(v0.y,v1.y,v2.y,v3.y,1)
    STCOL(v0.z,v1.z,v2.z,v3.z,2)
    STCOL(v0.w,v1.w,v2.w,v3.w,3)
#undef STCOL
  }
  __syncthreads();

  f32x4 acc[9];
  #pragma unroll
  for (int t=0;t<9;++t) acc[t] = (f32x4){0.f,0.f,0.f,0.f};

  // phase 1: TT = X^T * F   (tile gt: M-tile mt over T-cols, N-tile nt over T-rows)
  #pragma unroll
  for (int t=0;t<9;++t){
    int gt = wid*9 + t;
    int mt = gt/6, nt = gt - mt*6;
    int arow = mt*16 + l15;
    #pragma unroll
    for (int kb=0;kb<3;++kb){
      bf16x8 ah = *(const bf16x8*)&Xh[arow*104 + kb*32 + l4*8];
      bf16x8 al = *(const bf16x8*)&Xl[arow*104 + kb*32 + l4*8];
      const bf16x8 bh = *(const bf16x8*)(Fh + (size_t)((kb*6+nt)*64 + lane)*8);
      const bf16x8 bl = *(const bf16x8*)(Fl + (size_t)((kb*6+nt)*64 + lane)*8);
      acc[t] = __builtin_amdgcn_mfma_f32_16x16x32_bf16(al, bh, acc[t], 0,0,0);
      acc[t] = __builtin_amdgcn_mfma_f32_16x16x32_bf16(ah, bl, acc[t], 0,0,0);
      acc[t] = __builtin_amdgcn_mfma_f32_16x16x32_bf16(ah, bh, acc[t], 0,0,0);
    }
  }
  __syncthreads();   // all phase-1 LDS reads complete before overwrite

  // write T (row-major, hi/lo) over X's LDS: lane holds T[i=nt*16+l15][j=mt*16+l4*4+p]
  #pragma unroll
  for (int t=0;t<9;++t){
    int gt = wid*9 + t;
    int mt = gt/6, nt = gt - mt*6;
    int ti = nt*16 + l15, tj = mt*16 + l4*4;
    s16x4 hv, lv; short hs, ls;
    split2(acc[t][0],hs,ls); hv[0]=hs; lv[0]=ls;
    split2(acc[t][1],hs,ls); hv[1]=hs; lv[1]=ls;
    split2(acc[t][2],hs,ls); hv[2]=hs; lv[2]=ls;
    split2(acc[t][3],hs,ls); hv[3]=hs; lv[3]=ls;
    *(s16x4*)&Xh[ti*104+tj] = hv;
    *(s16x4*)&Xl[ti*104+tj] = lv;
  }
  #pragma unroll
  for (int t=0;t<9;++t) acc[t] = (f32x4){0.f,0.f,0.f,0.f};
  __syncthreads();

  // phase 2: Y = T * F   (tile gt: it over Y-rows, jt over Y-cols)
  #pragma unroll
  for (int t=0;t<9;++t){
    int gt = wid*9 + t;
    int it = gt/6, jt = gt - it*6;
    int arow = it*16 + l15;
    #pragma unroll
    for (int kb=0;kb<3;++kb){
      bf16x8 ah = *(const bf16x8*)&Xh[arow*104 + kb*32 + l4*8];
      bf16x8 al = *(const bf16x8*)&Xl[arow*104 + kb*32 + l4*8];
      const bf16x8 bh = *(const bf16x8*)(Fh + (size_t)((kb*6+jt)*64 + lane)*8);
      const bf16x8 bl = *(const bf16x8*)(Fl + (size_t)((kb*6+jt)*64 + lane)*8);
      acc[t] = __builtin_amdgcn_mfma_f32_16x16x32_bf16(al, bh, acc[t], 0,0,0);
      acc[t] = __builtin_amdgcn_mfma_f32_16x16x32_bf16(ah, bl, acc[t], 0,0,0);
      acc[t] = __builtin_amdgcn_mfma_f32_16x16x32_bf16(ah, bh, acc[t], 0,0,0);
    }
  }

  float* dst = out + (size_t)blockIdx.x*NPIX;
  if (mode == 2){
    #pragma unroll
    for (int t=0;t<9;++t){
      int gt = wid*9 + t;
      int it = gt/6, jt = gt - it*6;
      int i0 = it*16 + l4*4, j = jt*16 + l15;
      dst[(i0+0)*96 + j] = acc[t][0];
      dst[(i0+1)*96 + j] = acc[t][1];
      dst[(i0+2)*96 + j] = acc[t][2];
      dst[(i0+3)*96 + j] = acc[t][3];
    }
  } else if (mode == 0){
    float lmn = 3.4e38f, lmx = 0.f;
    #pragma unroll
    for (int t=0;t<9;++t){
      #pragma unroll
      for (int p=0;p<4;++p){ float a = fabsf(acc[t][p]); lmn = fminf(lmn,a); lmx = fmaxf(lmx,a); }
    }
    red[tid]=lmn; red[256+tid]=lmx; __syncthreads();
    for (int o=128;o;o>>=1){
      if (tid<o){ red[tid]=fminf(red[tid],red[tid+o]); red[256+tid]=fmaxf(red[256+tid],red[256+tid+o]); }
      __syncthreads();
    }
    float mn = red[0], inv = 1.f/(red[256]+1e-6f);
    #pragma unroll
    for (int t=0;t<9;++t){
      int gt = wid*9 + t;
      int it = gt/6, jt = gt - it*6;
      int i0 = it*16 + l4*4, j = jt*16 + l15;
      dst[(i0+0)*96 + j] = (fabsf(acc[t][0])-mn)*inv;
      dst[(i0+1)*96 + j] = (fabsf(acc[t][1])-mn)*inv;
      dst[(i0+2)*96 + j] = (fabsf(acc[t][2])-mn)*inv;
      dst[(i0+3)*96 + j] = (fabsf(acc[t][3])-mn)*inv;
    }
  } else { // mode 1
    float ls = 0.f;
    #pragma unroll
    for (int t=0;t<9;++t){
      #pragma unroll
      for (int p=0;p<4;++p) ls += acc[t][p];
    }
    red[tid]=ls; __syncthreads();
    for (int o=128;o;o>>=1){ if (tid<o) red[tid]+=red[tid+o]; __syncthreads(); }
    float mean = red[0]*(1.f/9216.f);
    #pragma unroll
    for (int t=0;t<9;++t){
      int gt = wid*9 + t;
      int it = gt/6, jt = gt - it*6;
      int i0 = it*16 + l4*4, j = jt*16 + l15;
      #pragma unroll
      for (int p=0;p<4;++p){
        float v = acc[t][p];
        dst[(i0+p)*96 + j] = v * sigm(5.f*(fabsf(v)-mean));
      }
    }
  }
}

// ---------------- channel mean of freq_norm ----------------
__global__ void k_chmean(const float* __restrict__ A, float* __restrict__ FNM){
  int px = blockIdx.x*256 + threadIdx.x;      // 0..73727
  int b = px/NPIX, p = px - b*NPIX;
  const float* base = A + (size_t)b*Cc*NPIX + p;
  float s = 0.f;
  #pragma unroll 8
  for (int c=0;c<Cc;++c) s += base[(size_t)c*NPIX];
  FNM[px] = s*(1.f/256.f);
}

// ---------------- 3x3 conv (1ch) + partial BN1 stats ----------------
__global__ void k_conv3(const float* __restrict__ FNM, const float* __restrict__ w9,
                        float* __restrict__ E, float* __restrict__ P3){
  __shared__ float rs[256], rq[256];
  int px = blockIdx.x*256 + threadIdx.x;
  int b = px/NPIX, p = px - b*NPIX;
  int h = p/96, w = p - h*96;
  const float* base = FNM + b*NPIX;
  float a = 0.f;
  #pragma unroll
  for (int dy=0;dy<3;++dy){
    int hh = h+dy-1;
    if (hh>=0 && hh<96){
      #pragma unroll
      for (int dx=0;dx<3;++dx){
        int ww2 = w+dx-1;
        if (ww2>=0 && ww2<96) a = fmaf(base[hh*96+ww2], w9[dy*3+dx], a);
      }
    }
  }
  E[px] = a;
  rs[threadIdx.x]=a; rq[threadIdx.x]=a*a; __syncthreads();
  for (int o=128;o;o>>=1){
    if (threadIdx.x<o){ rs[threadIdx.x]+=rs[threadIdx.x+o]; rq[threadIdx.x]+=rq[threadIdx.x+o]; }
    __syncthreads();
  }
  if (threadIdx.x==0){ P3[2*blockIdx.x]=rs[0]; P3[2*blockIdx.x+1]=rq[0]; }
}

__global__ void k_red576(const float* __restrict__ P3, float* __restrict__ ST1){
  __shared__ float rs[256], rq[256];
  float s=0.f,q=0.f;
  for (int i=threadIdx.x;i<288;i+=256){ s+=P3[2*i]; q+=P3[2*i+1]; }
  rs[threadIdx.x]=s; rq[threadIdx.x]=q; __syncthreads();
  for (int o=128;o;o>>=1){
    if (threadIdx.x<o){ rs[threadIdx.x]+=rs[threadIdx.x+o]; rq[threadIdx.x]+=rq[threadIdx.x+o]; }
    __syncthreads();
  }
  if (threadIdx.x==0){ ST1[0]=rs[0]; ST1[1]=rq[0]; }
}

// ---------------- BN1+relu, pooled, noise_global, mask ----------------
__global__ void k_mask(const float* __restrict__ E, const float* __restrict__ ST1,
                       const float* __restrict__ g1, const float* __restrict__ b1,
                       const float* __restrict__ nw, const float* __restrict__ nb,
                       float* __restrict__ MASK){
  __shared__ float les[NPIX];
  __shared__ float red[256];
  int b = blockIdx.x, tid = threadIdx.x;
  float m = ST1[0]*(1.f/BN1N);
  float v = ST1[1]*(1.f/BN1N) - m*m;
  float rstd = rsqrtf(v + 1e-5f);
  float ga = g1[0], be = b1[0];
  float local = 0.f;
  for (int p=tid;p<NPIX;p+=256){
    float le = fmaxf(0.f, (E[b*NPIX+p]-m)*rstd*ga + be);
    les[p] = le; local += le;
  }
  red[tid]=local; __syncthreads();
  for (int o=128;o;o>>=1){ if (tid<o) red[tid]+=red[tid+o]; __syncthreads(); }
  float ng = sigm(red[0]*(1.f/9216.f)*nw[0] + nb[0]);
  for (int p=tid;p<NPIX;p+=256)
    MASK[b*NPIX+p] = sigm(1.f - les[p]) * ng;
}

// ---------------- NCHW -> NHWC transpose ----------------
__global__ void k_tr(const float* __restrict__ x, float* __restrict__ XT){
  __shared__ float tile[32][33];
  int pt = blockIdx.x*32, ct = blockIdx.y*32, b = blockIdx.z;
  int txd = threadIdx.x, tyd = threadIdx.y;
  #pragma unroll
  for (int q=0;q<4;++q){
    int c = ct + tyd + q*8;
    tile[tyd+q*8][txd] = x[(size_t)(b*Cc+c)*NPIX + pt + txd];
  }
  __syncthreads();
  #pragma unroll
  for (int q=0;q<4;++q){
    int p = pt + tyd + q*8;
    XT[(size_t)(b*NPIX+p)*Cc + ct + txd] = tile[txd][tyd+q*8];
  }
}

// ---------------- qkv GEMM (pass g covers heads 2g, 2g+1; N=192) ----------------
__global__ __launch_bounds__(256) void k_qkv(const float* __restrict__ XT, const float* __restrict__ Wq,
                                             const float* __restrict__ bq, float* __restrict__ qkv, int g){
  __shared__ __align__(16) float As[16*128];
  __shared__ __align__(16) float Bs[16*96];
  const int mt = blockIdx.x, nt = blockIdx.y;
  const int r0 = mt*128;
  const int tid = threadIdx.x;
  const int ty = tid>>4, tx = tid&15;
  float acc[8][6];
  #pragma unroll
  for (int a=0;a<8;++a){
    #pragma unroll
    for (int b=0;b<6;++b) acc[a][b]=0.f;
  }

  for (int k0=0;k0<256;k0+=16){
    #pragma unroll
    for (int it=0;it<2;++it){
      int f = tid + it*256;
      int i = f>>2, kq = f&3;
      int r = r0 + i;
      int win = r/144, l = r - win*144;
      int b = win>>6, wh = (win>>3)&7, wwi = win&7;
      int lh = l/12, lw = l - lh*12;
      int pix = (wh*12+lh)*96 + wwi*12+lw;
      float4 v = *(const float4*)&XT[((size_t)((b*NPIX)+pix))*256 + k0 + (kq<<2)];
      int kk = kq<<2;
      As[(kk+0)*128+i]=v.x; As[(kk+1)*128+i]=v.y; As[(kk+2)*128+i]=v.z; As[(kk+3)*128+i]=v.w;
    }
    #pragma unroll
    for (int it=0;it<2;++it){
      int f = tid + it*256;
      if (f < 384){
        int c = f>>2, kq = f&3;
        int cg = nt*96 + c;
        int t = cg>>6, hl = (cg>>5)&1, d = cg&31;
        int wrow = t*256 + (g*2+hl)*32 + d;
        float4 v = *(const float4*)&Wq[(size_t)wrow*256 + k0 + (kq<<2)];
        int kk = kq<<2;
        Bs[(kk+0)*96+c]=v.x; Bs[(kk+1)*96+c]=v.y; Bs[(kk+2)*96+c]=v.z; Bs[(kk+3)*96+c]=v.w;
      }
    }
    __syncthreads();
    #pragma unroll
    for (int k=0;k<16;++k){
      const float4* pa = (const float4*)&As[k*128 + ty*8];
      float4 a0 = pa[0], a1 = pa[1];
      float av[8] = {a0.x,a0.y,a0.z,a0.w,a1.x,a1.y,a1.z,a1.w};
      const float2* pb = (const float2*)&Bs[k*96];
      float2 b0 = pb[tx], b1 = pb[tx+16], b2 = pb[tx+32];
      float bv[6] = {b0.x,b0.y,b1.x,b1.y,b2.x,b2.y};
      #pragma unroll
      for (int ii=0;ii<8;++ii){
        #pragma unroll
        for (int jj=0;jj<6;++jj) acc[ii][jj] = fmaf(av[ii], bv[jj], acc[ii][jj]);
      }
    }
    __syncthreads();
  }
  #pragma unroll
  for (int ii=0;ii<8;++ii){
    int r = r0 + ty*8 + ii;
    int win = r/144, l = r - win*144;
    #pragma unroll
    for (int jj=0;jj<6;++jj){
      int s = jj>>1;
      int c = nt*96 + 2*tx + s*32 + (jj&1);
      int t = c>>6, hl = (c>>5)&1, d = c&31;
      float val = acc[ii][jj] + bq[t*256 + (g*2+hl)*32 + d];
      qkv[(size_t)t*QKV_TSEC + ((size_t)(win*2+hl)*144 + l)*32 + d] = val;
    }
  }
}

// ---------------- window attention (one block per window x head-local) ----------------
__global__ __launch_bounds__(192) void k_attn(const float* __restrict__ qkv, const float* __restrict__ rpb,
                                              float* __restrict__ O, int g){
  __shared__ __align__(16) float qt[32*144];
  __shared__ __align__(16) float Ks[144*32];
  __shared__ __align__(16) float Vs[144*32];
  __shared__ float rpbs[532];
  const int win = blockIdx.x, hl = blockIdx.y;
  const int head = g*2 + hl;
  const int tid = threadIdx.x;
  const float* Qg = qkv + ((size_t)(win*2+hl)*144)*32;
  const float* Kg = Qg + QKV_TSEC;
  const float* Vg = Qg + 2*(size_t)QKV_TSEC;
  for (int t=tid; t<4608; t+=192){
    Ks[t] = Kg[t]; Vs[t] = Vg[t];
    int l = t>>5, d = t&31;
    qt[d*144+l] = Qg[t];
  }
  for (int t=tid; t<529; t+=192) rpbs[t] = rpb[t*8 + head];
  __syncthreads();

  int r = tid;
  if (r < 144){
    float q[32];
    #pragma unroll
    for (int d=0;d<32;++d) q[d] = qt[d*144+r];
    float o[32];
    #pragma unroll
    for (int d=0;d<32;++d) o[d]=0.f;
    float m = -3.4e38f, sum = 0.f;
    int rh = r/12, rw = r - rh*12;
    int jh = 0, jw = 0;
    for (int j=0;j<144;++j){
      const float4* kp = (const float4*)&Ks[j*32];
      float s0=0,s1=0,s2=0,s3=0;
      #pragma unroll
      for (int t=0;t<8;++t){
        float4 kv = kp[t];
        s0 = fmaf(q[4*t+0],kv.x,s0); s1 = fmaf(q[4*t+1],kv.y,s1);
        s2 = fmaf(q[4*t+2],kv.z,s2); s3 = fmaf(q[4*t+3],kv.w,s3);
      }
      float s = ((s0+s1)+(s2+s3))*SCALE_ + rpbs[(rh-jh+11)*23 + (rw-jw+11)];
      float mn2 = fmaxf(m, s);
      if (mn2 > m){
        float corr = __expf(m - mn2);
        sum *= corr;
        #pragma unroll
        for (int d=0;d<32;++d) o[d]*=corr;
        m = mn2;
      }
      float p = __expf(s - m);
      sum += p;
      const float4* vp = (const float4*)&Vs[j*32];
      #pragma unroll
      for (int t=0;t<8;++t){
        float4 vv = vp[t];
        o[4*t+0]=fmaf(p,vv.x,o[4*t+0]); o[4*t+1]=fmaf(p,vv.y,o[4*t+1]);
        o[4*t+2]=fmaf(p,vv.z,o[4*t+2]); o[4*t+3]=fmaf(p,vv.w,o[4*t+3]);
      }
      if (++jw==12){ jw=0; ++jh; }
    }
    float inv = 1.f/sum;
    float* dst = O + ((size_t)(win*144+r))*256 + head*32;
    #pragma unroll
    for (int t=0;t<8;++t){
      float4 t4 = { o[4*t]*inv, o[4*t+1]*inv, o[4*t+2]*inv, o[4*t+3]*inv };
      *(float4*)&dst[4*t] = t4;
    }
  }
}

// ---------------- depthwise LPE * mask -> Y1 += ----------------
__global__ void k_lpe(const float* __restrict__ x, const float* __restrict__ lw,
                      const float* __restrict__ lb, const float* __restrict__ ls,
                      const float* __restrict__ MASK, float* __restrict__ Y1){
  float scale = ls[0];
  for (size_t idx = (size_t)blockIdx.x*256 + threadIdx.x; idx < (size_t)Bb*Cc*NPIX; idx += (size_t)gridDim.x*256){
    int pc = (int)(idx/NPIX); int p = (int)(idx - (size_t)pc*NPIX);
    int b = pc>>8, c = pc&255;
    int h = p/96, w = p - h*96;
    const float* xp = x + (size_t)pc*NPIX;
    const float* wp = lw + c*9;
    float a = 0.f;
    #pragma unroll
    for (int dy=0;dy<3;++dy){
      int hh = h+dy-1;
      if (hh>=0 && hh<96){
        #pragma unroll
        for (int dx=0;dx<3;++dx){
          int ww2 = w+dx-1;
          if (ww2>=0 && ww2<96) a = fmaf(xp[hh*96+ww2], wp[dy*3+dx], a);
        }
      }
    }
    Y1[idx] += (a + lb[c]) * scale * MASK[b*NPIX+p];
  }
}

// ---------------- proj GEMM -> PROJ token-major [token][256], bias fused ----------------
__global__ __launch_bounds__(256) void k_proj(const float* __restrict__ O, const float* __restrict__ Wp,
                                              const float* __restrict__ bp, float* __restrict__ PROJ){
  __shared__ __align__(16) float As[16*128];
  __shared__ __align__(16) float Bs[16*128];
  const int mt = blockIdx.x, nt = blockIdx.y;
  const int r0 = mt*128, c0 = nt*128;
  const int tid = threadIdx.x;
  const int ty = tid>>4, tx = tid&15;
  float acc[8][8];
  #pragma unroll
  for (int a=0;a<8;++a){
    #pragma unroll
    for (int b=0;b<8;++b) acc[a][b]=0.f;
  }

  for (int k0=0;k0<256;k0+=16){
    #pragma unroll
    for (int it=0;it<2;++it){
      int f = tid + it*256;
      int i = f>>2, kq = f&3;
      float4 v = *(const float4*)&O[((size_t)(r0+i))*256 + k0 + (kq<<2)];
      int kk = kq<<2;
      As[(kk+0)*128+i]=v.x; As[(kk+1)*128+i]=v.y; As[(kk+2)*128+i]=v.z; As[(kk+3)*128+i]=v.w;
    }
    #pragma unroll
    for (int it=0;it<2;++it){
      int f = tid + it*256;
      int c = f>>2, kq = f&3;
      float4 v = *(const float4*)&Wp[((size_t)(c0+c))*256 + k0 + (kq<<2)];
      int kk = kq<<2;
      Bs[(kk+0)*128+c]=v.x; Bs[(kk+1)*128+c]=v.y; Bs[(kk+2)*128+c]=v.z; Bs[(kk+3)*128+c]=v.w;
    }
    __syncthreads();
    #pragma unroll
    for (int k=0;k<16;++k){
      const float4* pa = (const float4*)&As[k*128 + ty*8];
      float4 a0 = pa[0], a1 = pa[1];
      float av[8] = {a0.x,a0.y,a0.z,a0.w,a1.x,a1.y,a1.z,a1.w};
      const float4* pb = (const float4*)&Bs[k*128];
      float4 b0 = pb[tx], b1 = pb[tx+16];
      float bv[8] = {b0.x,b0.y,b0.z,b0.w,b1.x,b1.y,b1.z,b1.w};
      #pragma unroll
      for (int ii=0;ii<8;++ii){
        #pragma unroll
        for (int jj=0;jj<8;++jj) acc[ii][jj] = fmaf(av[ii], bv[jj], acc[ii][jj]);
      }
    }
    __syncthreads();
  }
  const float4 bp0 = *(const float4*)&bp[c0 + 4*tx];
  const float4 bp1 = *(const float4*)&bp[c0 + 64 + 4*tx];
  #pragma unroll
  for (int ii=0;ii<8;++ii){
    int r = r0 + ty*8 + ii;
    float* pp = PROJ + (size_t)r*256 + c0;
    float4 v0 = { acc[ii][0]+bp0.x, acc[ii][1]+bp0.y, acc[ii][2]+bp0.z, acc[ii][3]+bp0.w };
    float4 v1 = { acc[ii][4]+bp1.x, acc[ii][5]+bp1.y, acc[ii][6]+bp1.z, acc[ii][7]+bp1.w };
    *(float4*)&pp[4*tx] = v0;
    *(float4*)&pp[64 + 4*tx] = v1;
  }
}

// ---------------- token-major PROJ -> NCHW Y1 (LDS transpose) ----------------
__global__ __launch_bounds__(256) void k_merge(const float* __restrict__ PROJ, float* __restrict__ Y1){
  __shared__ float T[96*65];
  const int bx = blockIdx.x;          // b*96 + h
  const int b = bx/96, h = bx - b*96;
  const int wh = h/12, lh = h - wh*12;
  const int c0 = blockIdx.y*64;
  const int t = threadIdx.x;
  const int wave = t>>6, lane = t&63;
  for (int it=0; it<24; ++it){
    int tok = wave*24 + it;
    int wwi = tok/12, lw = tok - wwi*12;
    int gtok = (b*64 + wh*8 + wwi)*144 + lh*12 + lw;
    T[tok*65 + lane] = PROJ[(size_t)gtok*256 + c0 + lane];
  }
  __syncthreads();
  const int cl = t>>2, p0 = (t&3)*24;
  float* dst = Y1 + ((size_t)(b*Cc + c0 + cl))*NPIX + h*96 + p0;
  #pragma unroll
  for (int i=0;i<24;i+=4){
    float4 v = { T[(p0+i)*65+cl], T[(p0+i+1)*65+cl], T[(p0+i+2)*65+cl], T[(p0+i+3)*65+cl] };
    *(float4*)&dst[i] = v;
  }
}

// ---------------- 1x1 refine conv: Z = fr_w @ (x + XF) ----------------
__global__ __launch_bounds__(256) void k_conv1x1(const float* __restrict__ x, const float* __restrict__ XF,
                                                 const float* __restrict__ Wf, float* __restrict__ Z){
  __shared__ __align__(16) float As[16*128];
  __shared__ __align__(16) float Bs[16*128];
  const int mt = blockIdx.x, nt = blockIdx.y;
  const int gp0 = mt*128;
  const int b = gp0/NPIX, p0 = gp0 - b*NPIX;
  const int c0 = nt*128;
  const int tid = threadIdx.x;
  const int ty = tid>>4, tx = tid&15;
  float acc[8][8];
  #pragma unroll
  for (int a=0;a<8;++a){
    #pragma unroll
    for (int bb=0;bb<8;++bb) acc[a][bb]=0.f;
  }

  for (int k0=0;k0<256;k0+=16){
    #pragma unroll
    for (int it=0;it<2;++it){
      int f = tid + it*256;
      int k = f>>5, i4 = f&31;
      size_t off = ((size_t)(b*Cc + k0 + k))*NPIX + p0 + i4*4;
      float4 va = *(const float4*)&x[off];
      float4 vb = *(const float4*)&XF[off];
      float4 s = { va.x+vb.x, va.y+vb.y, va.z+vb.z, va.w+vb.w };
      *(float4*)&As[k*128 + i4*4] = s;
    }
    #pragma unroll
    for (int it=0;it<2;++it){
      int f = tid + it*256;
      int c = f>>2, kq = f&3;
      float4 v = *(const float4*)&Wf[((size_t)(c0+c))*256 + k0 + (kq<<2)];
      int kk = kq<<2;
      Bs[(kk+0)*128+c]=v.x; Bs[(kk+1)*128+c]=v.y; Bs[(kk+2)*128+c]=v.z; Bs[(kk+3)*128+c]=v.w;
    }
    __syncthreads();
    #pragma unroll
    for (int k=0;k<16;++k){
      const float4* pa = (const float4*)&As[k*128 + ty*8];
      float4 a0 = pa[0], a1 = pa[1];
      float av[8] = {a0.x,a0.y,a0.z,a0.w,a1.x,a1.y,a1.z,a1.w};
      const float4* pb = (const float4*)&Bs[k*128];
      float4 b0 = pb[tx], b1 = pb[tx+16];
      float bv[8] = {b0.x,b0.y,b0.z,b0.w,b1.x,b1.y,b1.z,b1.w};
      #pragma unroll
      for (int ii=0;ii<8;++ii){
        #pragma unroll
        for (int jj=0;jj<8;++jj) acc[ii][jj] = fmaf(av[ii], bv[jj], acc[ii][jj]);
      }
    }
    __syncthreads();
  }
  #pragma unroll
  for (int jj=0;jj<8;++jj){
    int co = c0 + ((jj<4)? 4*tx+jj : 64 + 4*tx + (jj-4));
    float4 lo = {acc[0][jj],acc[1][jj],acc[2][jj],acc[3][jj]};
    float4 hi = {acc[4][jj],acc[5][jj],acc[6][jj],acc[7][jj]};
    float* zp = Z + ((size_t)(b*Cc+co))*NPIX + p0 + ty*8;
    *(float4*)zp = lo;
    *(float4*)(zp+4) = hi;
  }
}

// ---------------- BN2 stats (per channel over B,H,W) ----------------
__global__ void k_bnstat(const float* __restrict__ Z, float* __restrict__ BN2){
  __shared__ float rs[256], rq[256];
  int c = blockIdx.x, tid = threadIdx.x;
  float s=0.f,q=0.f;
  for (int b=0;b<Bb;++b){
    const float* pl = Z + ((size_t)(b*Cc+c))*NPIX;
    for (int i=tid;i<NPIX/4;i+=256){
      float4 v = *(const float4*)&pl[i*4];
      s += v.x+v.y+v.z+v.w;
      q += v.x*v.x + v.y*v.y + v.z*v.z + v.w*v.w;
    }
  }
  rs[tid]=s; rq[tid]=q; __syncthreads();
  for (int o=128;o;o>>=1){
    if (tid<o){ rs[tid]+=rs[tid+o]; rq[tid]+=rq[tid+o]; }
    __syncthreads();
  }
  if (tid==0){ BN2[c]=rs[0]; BN2[256+c]=rq[0]; }
}

// ---------------- final: BN2 + exact GELU ----------------
__global__ void k_final(const float* __restrict__ Z, const float* __restrict__ BN2,
                        const float* __restrict__ g2, const float* __restrict__ b2,
                        float* __restrict__ out){
  size_t f4 = (size_t)blockIdx.x*256 + threadIdx.x;   // 4718592 total
  size_t base = f4*4;
  int c = (int)((base/NPIX) & 255);
  float m = BN2[c]*(1.f/BN1N);
  float v = BN2[256+c]*(1.f/BN1N) - m*m;
  float rstd = rsqrtf(v+1e-5f);
  float ga = g2[c], be = b2[c];
  float4 z = *(const float4*)&Z[base];
  float4 r;
  float y;
  y = (z.x-m)*rstd*ga + be; r.x = 0.5f*y*(1.f+erff(y*GELC));
  y = (z.y-m)*rstd*ga + be; r.y = 0.5f*y*(1.f+erff(y*GELC));
  y = (z.z-m)*rstd*ga + be; r.z = 0.5f*y*(1.f+erff(y*GELC));
  y = (z.w-m)*rstd*ga + be; r.w = 0.5f*y*(1.f+erff(y*GELC));
  *(float4*)&out[base] = r;
}

// ---------------- launch ----------------
extern "C" void kernel_launch(void* const* d_in, const int* in_sizes, int n_in,
                              void* d_out, int out_size, void* d_ws, size_t ws_size,
                              hipStream_t stream){
  const float* x      = (const float*)d_in[0];
  const float* qkv_w  = (const float*)d_in[1];
  const float* qkv_b  = (const float*)d_in[2];
  const float* proj_w = (const float*)d_in[3];
  const float* proj_b = (const float*)d_in[4];
  const float* lpe_w  = (const float*)d_in[5];
  const float* lpe_b  = (const float*)d_in[6];
  const float* lpe_s  = (const float*)d_in[7];
  const float* rpb    = (const float*)d_in[8];
  const float* ec_w   = (const float*)d_in[9];
  const float* bn1_g  = (const float*)d_in[10];
  const float* bn1_b  = (const float*)d_in[11];
  const float* nl_w   = (const float*)d_in[12];
  const float* nl_b   = (const float*)d_in[13];
  const float* fr_w   = (const float*)d_in[14];
  const float* bn2_g  = (const float*)d_in[15];
  const float* bn2_b  = (const float*)d_in[16];
  float* outp = (float*)d_out;

  float* WS   = (float*)d_ws;       // needs ~228 MB
  short* FR   = (short*)(WS + OFF_DT);
  short* DFh  = FR;
  short* DFl  = FR + 9216;
  short* MFh  = FR + 18432;
  short* MFl  = FR + 27648;
  float* FNM  = WS + OFF_FNM;
  float* E    = WS + OFF_E;
  float* MASK = WS + OFF_MASK;
  float* P3   = WS + OFF_P3;
  float* ST1  = WS + OFF_ST1;
  float* BN2  = WS + OFF_BN2;
  float* BUF0 = WS + OFF_BUF0;      // XT -> PROJ -> XF
  float* BUF1 = WS + OFF_BUF1;      // QKV -> Y1 -> Z
  float* BUF2 = WS + OFF_BUF2;      // A(fn) -> O -> G

  k_mat<<<72,256,0,stream>>>(DFh, DFl, MFh, MFl);
  // freq detector: |dct2(x)| plane-normalized -> BUF2
  k_plane<<<NPLANE,256,0,stream>>>(x, BUF2, DFh, DFl, 0);
  k_chmean<<<288,256,0,stream>>>(BUF2, FNM);
  k_conv3<<<288,256,0,stream>>>(FNM, ec_w, E, P3);
  k_red576<<<1,256,0,stream>>>(P3, ST1);
  k_mask<<<8,256,0,stream>>>(E, ST1, bn1_g, bn1_b, nl_w, nl_b, MASK);
  // attention
  k_tr<<<dim3(288,8,8),dim3(32,8),0,stream>>>(x, BUF0);
  for (int g=0; g<4; ++g){
    k_qkv<<<dim3(576,2),256,0,stream>>>(BUF0, qkv_w, qkv_b, BUF1, g);
    k_attn<<<dim3(512,2),192,0,stream>>>(BUF1, rpb, BUF2, g);
  }
  k_proj<<<dim3(576,2),256,0,stream>>>(BUF2, proj_w, proj_b, BUF0);   // PROJ token-major
  k_merge<<<dim3(768,4),256,0,stream>>>(BUF0, BUF1);                  // Y1 = attn (NCHW)
  k_lpe<<<4096,256,0,stream>>>(x, lpe_w, lpe_b, lpe_s, MASK, BUF1);   // Y1 += lpe*mask
  // frequency soft gate
  k_plane<<<NPLANE,256,0,stream>>>(BUF1, BUF2, DFh, DFl, 1);          // G = freq2*gate
  k_plane<<<NPLANE,256,0,stream>>>(BUF2, BUF0, MFh, MFl, 2);          // XF = idct2(G)
  // refine + BN2 + gelu
  k_conv1x1<<<dim3(576,2),256,0,stream>>>(x, BUF0, fr_w, BUF1);       // Z
  k_bnstat<<<256,256,0,stream>>>(BUF1, BN2);
  k_final<<<18432,256,0,stream>>>(BUF1, BN2, bn2_g, bn2_b, outp);
}